// Round 3
// baseline (194.797 us; speedup 1.0000x reference)
//
#include <hip/hip_runtime.h>
#include <hip/hip_bf16.h>

typedef __attribute__((ext_vector_type(8))) short bf16x8;
typedef __attribute__((ext_vector_type(4))) float f32x4;
typedef __attribute__((ext_vector_type(4))) int i32x4;

// ---------- helpers ----------
static __device__ __forceinline__ void gload_lds16(const void* g, void* l) {
  __builtin_amdgcn_global_load_lds((const __attribute__((address_space(1))) void*)g,
                                   (__attribute__((address_space(3))) void*)l,
                                   16, 0, 0);
}

// f32 -> bf16 bits, round-to-nearest-even
static __device__ __forceinline__ unsigned short f2bf(float x) {
  unsigned int u = __float_as_uint(x);
  u += 0x7fffu + ((u >> 16) & 1u);
  return (unsigned short)(u >> 16);
}

// ---------------- shared 128x128 GEMM core: BK=64, 4 waves (2x2), 16x16x32 bf16
// C[M,N] = A[M,K](row-major,lda) x Bt[N,K]^T(row-major,ldb)
static __device__ __forceinline__ void gemm_core(
    const unsigned short* __restrict__ A, int lda,
    const unsigned short* __restrict__ Bt, int ldb,
    int Kd, int brow, int bcol,
    unsigned short* As, unsigned short* Bs,
    int wid, int lane, f32x4 acc[4][4])
{
  const int wr = wid >> 1, wc = wid & 1;
  const int l15 = lane & 15, l4 = lane >> 4;
  const int foff = wid * 512 + lane * 8;

  for (int k0 = 0; k0 < Kd; k0 += 64) {
#pragma unroll
    for (int c = 0; c < 4; ++c) {
      int f = c * 2048 + foff;
      int r = f >> 6, kc = f & 63;
      gload_lds16(A + (size_t)(brow + r) * lda + k0 + kc, As + c * 2048 + wid * 512);
    }
#pragma unroll
    for (int c = 0; c < 4; ++c) {
      int f = c * 2048 + foff;
      int r = f >> 6, kc = f & 63;
      gload_lds16(Bt + (size_t)(bcol + r) * ldb + k0 + kc, Bs + c * 2048 + wid * 512);
    }
    __syncthreads();
#pragma unroll
    for (int kk = 0; kk < 2; ++kk) {
      const int ko = kk * 32 + l4 * 8;
      bf16x8 af[4], bfv[4];
#pragma unroll
      for (int m = 0; m < 4; ++m)
        af[m] = *(const bf16x8*)(As + (wr * 64 + m * 16 + l15) * 64 + ko);
#pragma unroll
      for (int n = 0; n < 4; ++n)
        bfv[n] = *(const bf16x8*)(Bs + (wc * 64 + n * 16 + l15) * 64 + ko);
#pragma unroll
      for (int m = 0; m < 4; ++m)
#pragma unroll
        for (int n = 0; n < 4; ++n)
          acc[m][n] = __builtin_amdgcn_mfma_f32_16x16x32_bf16(af[m], bfv[n], acc[m][n], 0, 0, 0);
    }
    __syncthreads();
  }
}

// ---------------- standalone GEMM (scores / read paths)
// EPI 0: write f32 C (scores)
// EPI 1: v*=(*fscale); write bf16 into Cb (ld=ldcb)   [read path]
template <int EPI>
__global__ __launch_bounds__(256)
void gemm_bt(const unsigned short* __restrict__ A, int lda,
             const unsigned short* __restrict__ Bt, int ldb,
             int Kd, int Nd,
             float* __restrict__ Cf,
             unsigned short* __restrict__ Cb, int ldcb,
             const float* __restrict__ fscale)
{
  __shared__ unsigned short As[128 * 64];
  __shared__ unsigned short Bs[128 * 64];
  const int tid  = threadIdx.x;
  const int wid  = tid >> 6;
  const int lane = tid & 63;

  // T1 XCD swizzle (nwg % 8 == 0 -> bijective)
  const int nwg  = gridDim.x * gridDim.y;
  const int flat = blockIdx.y * gridDim.x + blockIdx.x;
  const int swz  = (flat & 7) * (nwg >> 3) + (flat >> 3);
  const int bx   = swz % gridDim.x;
  const int by   = swz / gridDim.x;

  const int brow = by * 128;
  const int bcol = bx * 128;
  const int wr = wid >> 1, wc = wid & 1;
  const int l15 = lane & 15, l4 = lane >> 4;

  f32x4 acc[4][4] = {};
  gemm_core(A, lda, Bt, ldb, Kd, brow, bcol, As, Bs, wid, lane, acc);

  // C/D frag mapping (m89-verified): col = lane&15, row = (lane>>4)*4 + j
  float fs = 1.0f;
  if constexpr (EPI == 1) fs = *fscale;
#pragma unroll
  for (int m = 0; m < 4; ++m) {
    int row0 = brow + wr * 64 + m * 16 + l4 * 4;
#pragma unroll
    for (int j = 0; j < 4; ++j) {
      int row = row0 + j;
#pragma unroll
      for (int n = 0; n < 4; ++n) {
        int col = bcol + wc * 64 + n * 16 + l15;
        float v = acc[m][n][j];
        if constexpr (EPI == 0) {
          Cf[(size_t)row * Nd + col] = v;
        } else {
          Cb[(size_t)row * ldcb + col] = f2bf(v * fs);
        }
      }
    }
  }
}

// ---------------- fused gate + out-projection GEMM (both read A=cat)
// grid dim3(16,64): after swizzle, bx<8 -> gate col-tile bx (K=2048, sigmoid
// rowsum epilogue); bx>=8 -> out col-tile bx-8 (K=1024, plain f32 write).
__global__ __launch_bounds__(256)
void gemm_gate_out(const unsigned short* __restrict__ cat,
                   const unsigned short* __restrict__ gwt,
                   const unsigned short* __restrict__ owt,
                   const float* __restrict__ gb,
                   float* __restrict__ gsum,
                   float* __restrict__ outpre)
{
  __shared__ unsigned short As[128 * 64];
  __shared__ unsigned short Bs[128 * 64];
  const int tid  = threadIdx.x;
  const int wid  = tid >> 6;
  const int lane = tid & 63;

  const int nwg  = 16 * 64;  // 1024
  const int flat = blockIdx.y * 16 + blockIdx.x;
  const int swz  = (flat & 7) * (nwg >> 3) + (flat >> 3);
  const int bx   = swz & 15;
  const int by   = swz >> 4;

  const int role = bx >> 3;        // 0 = gate, 1 = out
  const int brow = by * 128;
  const int bcol = (bx & 7) * 128;
  const int wr = wid >> 1, wc = wid & 1;
  const int l15 = lane & 15, l4 = lane >> 4;

  f32x4 acc[4][4] = {};
  if (role == 0)
    gemm_core(cat, 2048, gwt, 2048, 2048, brow, bcol, As, Bs, wid, lane, acc);
  else
    gemm_core(cat, 2048, owt, 1024, 1024, brow, bcol, As, Bs, wid, lane, acc);

  if (role == 0) {
    // sigmoid(v + gb[col]) summed per row -> atomicAdd gsum[row]
#pragma unroll
    for (int m = 0; m < 4; ++m) {
#pragma unroll
      for (int j = 0; j < 4; ++j) {
        float part = 0.0f;
#pragma unroll
        for (int n = 0; n < 4; ++n) {
          int col = bcol + wc * 64 + n * 16 + l15;
          float x = acc[m][n][j] + gb[col];
          part += 1.0f / (1.0f + __expf(-x));
        }
#pragma unroll
        for (int off = 1; off < 16; off <<= 1)
          part += __shfl_xor(part, off, 64);
        if (l15 == 0) {
          int row = brow + wr * 64 + m * 16 + l4 * 4 + j;
          atomicAdd(&gsum[row], part);
        }
      }
    }
  } else {
#pragma unroll
    for (int m = 0; m < 4; ++m) {
      int row0 = brow + wr * 64 + m * 16 + l4 * 4;
#pragma unroll
      for (int j = 0; j < 4; ++j) {
        int row = row0 + j;
#pragma unroll
        for (int n = 0; n < 4; ++n) {
          int col = bcol + wc * 64 + n * 16 + l15;
          outpre[(size_t)row * 1024 + col] = acc[m][n][j];
        }
      }
    }
  }
}

// ---------------- softmax over rows of 512: p = softmax(scores/sqrt(128) * w) -> bf16
__global__ __launch_bounds__(256)
void softmax_rows(const float* __restrict__ S, const float* __restrict__ W,
                  unsigned short* __restrict__ P)
{
  const int wid = threadIdx.x >> 6, lane = threadIdx.x & 63;
  const int row = blockIdx.x * 4 + wid;
  const size_t base = (size_t)row * 512 + lane * 8;
  const float sc = 0.08838834764831845f;  // 1/sqrt(128)
  f32x4 s0 = *(const f32x4*)(S + base);
  f32x4 s1 = *(const f32x4*)(S + base + 4);
  f32x4 w0 = *(const f32x4*)(W + base);
  f32x4 w1 = *(const f32x4*)(W + base + 4);
  float v[8];
#pragma unroll
  for (int i = 0; i < 4; ++i) { v[i] = s0[i] * sc * w0[i]; v[4 + i] = s1[i] * sc * w1[i]; }
  float mx = v[0];
#pragma unroll
  for (int i = 1; i < 8; ++i) mx = fmaxf(mx, v[i]);
#pragma unroll
  for (int off = 32; off >= 1; off >>= 1) mx = fmaxf(mx, __shfl_xor(mx, off, 64));
  float sum = 0.0f;
#pragma unroll
  for (int i = 0; i < 8; ++i) { v[i] = __expf(v[i] - mx); sum += v[i]; }
#pragma unroll
  for (int off = 32; off >= 1; off >>= 1) sum += __shfl_xor(sum, off, 64);
  const float inv = 1.0f / sum;
  union { unsigned short u[8]; i32x4 vec; } pk;
#pragma unroll
  for (int i = 0; i < 8; ++i) pk.u[i] = f2bf(v[i] * inv);
  *(i32x4*)(P + base) = pk.vec;
}

// ---------------- f32 -> bf16 convert (8 elems/thread)
__global__ __launch_bounds__(256)
void cvt_bf16x8(const float* __restrict__ in, unsigned short* __restrict__ out, int n8)
{
  int idx = blockIdx.x * 256 + threadIdx.x;
  if (idx >= n8) return;
  size_t f = (size_t)idx * 8;
  f32x4 a = *(const f32x4*)(in + f);
  f32x4 b = *(const f32x4*)(in + f + 4);
  union { unsigned short u[8]; i32x4 vec; } pk;
#pragma unroll
  for (int i = 0; i < 4; ++i) { pk.u[i] = f2bf(a[i]); pk.u[4 + i] = f2bf(b[i]); }
  *(i32x4*)(out + f) = pk.vec;
}

// ---------------- update_input -> cat[:, 1024:2048] bf16
__global__ __launch_bounds__(256)
void cvt_cat_upd(const float* __restrict__ upd, unsigned short* __restrict__ cat)
{
  int idx = blockIdx.x * 256 + threadIdx.x;  // exactly 1048576 threads
  size_t f = (size_t)idx * 8;
  int row = (int)(f >> 10);
  int col = (int)(f & 1023);
  f32x4 a = *(const f32x4*)(upd + f);
  f32x4 b = *(const f32x4*)(upd + f + 4);
  union { unsigned short u[8]; i32x4 vec; } pk;
#pragma unroll
  for (int i = 0; i < 4; ++i) { pk.u[i] = f2bf(a[i]); pk.u[4 + i] = f2bf(b[i]); }
  *(i32x4*)(cat + (size_t)row * 2048 + 1024 + col) = pk.vec;
}

// ---------------- tiled transpose f32[R,C] -> bf16[C,R]
__global__ __launch_bounds__(256)
void transpose_cvt(const float* __restrict__ in, unsigned short* __restrict__ out,
                   int R, int C)
{
  __shared__ float t[32][33];
  const int tx = threadIdx.x & 31, ty = threadIdx.x >> 5;
  const int c0 = blockIdx.x * 32, r0 = blockIdx.y * 32;
#pragma unroll
  for (int i = 0; i < 4; ++i)
    t[ty + i * 8][tx] = in[(size_t)(r0 + ty + i * 8) * C + c0 + tx];
  __syncthreads();
#pragma unroll
  for (int i = 0; i < 4; ++i)
    out[(size_t)(c0 + ty + i * 8) * R + r0 + tx] = f2bf(t[tx][ty + i * 8]);
}

// ---------------- LayerNorm over rows of 1024, block per row
// x = X[row]*(1 + gsum[row]/1024) + ob[col]  (gate scale + out bias fused here)
__global__ __launch_bounds__(256)
void ln_rows(const float* __restrict__ X, const float* __restrict__ gsum,
             const float* __restrict__ ob,
             const float* __restrict__ gamma, const float* __restrict__ beta,
             float* __restrict__ Y)
{
  const int row = blockIdx.x;
  const int tid = threadIdx.x;
  const size_t base = (size_t)row * 1024 + tid * 4;
  const float scl = 1.0f + gsum[row] * (1.0f / 1024.0f);
  f32x4 x = *(const f32x4*)(X + base);
  f32x4 bo = *(const f32x4*)(ob + tid * 4);
#pragma unroll
  for (int i = 0; i < 4; ++i) x[i] = x[i] * scl + bo[i];
  float s = x[0] + x[1] + x[2] + x[3];
  float q = x[0] * x[0] + x[1] * x[1] + x[2] * x[2] + x[3] * x[3];
#pragma unroll
  for (int off = 32; off >= 1; off >>= 1) {
    s += __shfl_xor(s, off, 64);
    q += __shfl_xor(q, off, 64);
  }
  __shared__ float ss[4], qq[4];
  const int wid = tid >> 6, lane = tid & 63;
  if (lane == 0) { ss[wid] = s; qq[wid] = q; }
  __syncthreads();
  s = ss[0] + ss[1] + ss[2] + ss[3];
  q = qq[0] + qq[1] + qq[2] + qq[3];
  const float mu = s * (1.0f / 1024.0f);
  const float var = q * (1.0f / 1024.0f) - mu * mu;
  const float r = rsqrtf(var + 1e-5f);
  f32x4 g = *(const f32x4*)(gamma + tid * 4);
  f32x4 b = *(const f32x4*)(beta + tid * 4);
  f32x4 y;
#pragma unroll
  for (int i = 0; i < 4; ++i) y[i] = (x[i] - mu) * r * g[i] + b[i];
  *(f32x4*)(Y + base) = y;
}

// ---------------- launch ----------------
extern "C" void kernel_launch(void* const* d_in, const int* in_sizes, int n_in,
                              void* d_out, int out_size, void* d_ws, size_t ws_size,
                              hipStream_t stream)
{
  (void)in_sizes; (void)n_in; (void)out_size; (void)ws_size;
  const float* q   = (const float*)d_in[0];   // [8192,1024]
  const float* mw  = (const float*)d_in[1];   // [8192,512]
  const float* upd = (const float*)d_in[2];   // [8192,1024]
  const float* mk  = (const float*)d_in[3];   // [512,1024]
  const float* mv  = (const float*)d_in[4];   // [512,1024]
  const float* dec = (const float*)d_in[5];   // scalar
  const float* gw  = (const float*)d_in[6];   // [2048,1024]
  const float* gb  = (const float*)d_in[7];   // [1024]
  const float* ow  = (const float*)d_in[8];   // [1024,1024]
  const float* ob  = (const float*)d_in[9];   // [1024]
  const float* lg  = (const float*)d_in[10];  // [1024]
  const float* lb  = (const float*)d_in[11];  // [1024]
  float* outp = (float*)d_out;
  char* ws = (char*)d_ws;

  // workspace layout (bytes); outpre overlays qb+scores after both are dead
  unsigned short* qb     = (unsigned short*)(ws + 0);          // 16.78 MB
  float*          scores = (float*)(ws + 16777216);            // 16.78 MB
  float*          outpre = (float*)(ws + 0);                   // 33.55 MB (reuse)
  unsigned short* kb     = (unsigned short*)(ws + 33554432);   // 1.05 MB
  unsigned short* vt     = (unsigned short*)(ws + 34603008);   // 1.05 MB
  unsigned short* gwt    = (unsigned short*)(ws + 35651584);   // 4.19 MB
  unsigned short* owt    = (unsigned short*)(ws + 39845888);   // 2.10 MB
  unsigned short* cat    = (unsigned short*)(ws + 41943040);   // 33.55 MB [8192,2048]
  unsigned short* probs  = (unsigned short*)(ws + 75497472);   // 8.39 MB
  float*          gsum   = (float*)(ws + 83886080);            // 32 KB
  // total ~84 MB

  // prep: bf16 conversions / transposes
  cvt_bf16x8<<<4096, 256, 0, stream>>>(q, qb, 1048576);
  cvt_bf16x8<<<256, 256, 0, stream>>>(mk, kb, 65536);
  cvt_cat_upd<<<4096, 256, 0, stream>>>(upd, cat);
  transpose_cvt<<<dim3(32, 16), 256, 0, stream>>>(mv, vt, 512, 1024);
  transpose_cvt<<<dim3(32, 64), 256, 0, stream>>>(gw, gwt, 2048, 1024);
  transpose_cvt<<<dim3(32, 32), 256, 0, stream>>>(ow, owt, 1024, 1024);
  hipMemsetAsync(gsum, 0, 8192 * sizeof(float), stream);

  // 1) scores = qb x kb^T   [8192,512], K=1024
  gemm_bt<0><<<dim3(4, 64), 256, 0, stream>>>(qb, 1024, kb, 1024, 1024, 512,
                                              scores, nullptr, 0, nullptr);
  // 2) probs = softmax(scores/sqrt(128)*w) -> bf16
  softmax_rows<<<2048, 256, 0, stream>>>(scores, mw, probs);
  // 3) read = probs x vt^T * decay -> bf16 into cat[:, :1024]
  gemm_bt<1><<<dim3(8, 64), 256, 0, stream>>>(probs, 512, vt, 512, 512, 1024,
                                              nullptr, cat, 2048, dec);
  // 4) fused: gate rowsums (sigmoid) + raw out-projection, both read cat
  gemm_gate_out<<<dim3(16, 64), 256, 0, stream>>>(cat, gwt, owt, gb, gsum, outpre);
  // 5) LayerNorm (applies gate scale + out bias) -> final output
  ln_rows<<<8192, 256, 0, stream>>>(outpre, gsum, ob, lg, lb, outp);
}

// Round 4
// 174.164 us; speedup vs baseline: 1.1185x; 1.1185x over previous
//
#include <hip/hip_runtime.h>
#include <hip/hip_bf16.h>

typedef __attribute__((ext_vector_type(8))) short bf16x8;
typedef __attribute__((ext_vector_type(4))) float f32x4;
typedef __attribute__((ext_vector_type(4))) int i32x4;

// ---------- helpers ----------
static __device__ __forceinline__ void gload_lds16(const void* g, void* l) {
  __builtin_amdgcn_global_load_lds((const __attribute__((address_space(1))) void*)g,
                                   (__attribute__((address_space(3))) void*)l,
                                   16, 0, 0);
}

// f32 -> bf16 bits, round-to-nearest-even
static __device__ __forceinline__ unsigned short f2bf(float x) {
  unsigned int u = __float_as_uint(x);
  u += 0x7fffu + ((u >> 16) & 1u);
  return (unsigned short)(u >> 16);
}

// ---------------- GEMM: C[M,N] = A[M,K](bf16,row,lda) x Bt[N,K]^T(bf16,row,ldb)
// 128x64 tile, BK=64, 256 threads = 4 waves (2Mx2N), per-wave 64x32, acc[4][2].
// Grid: (Nd/64, M/128). 4 blocks/CU for our 1024-block launches (occupancy fix).
// EPI 0: write f32 C (scores)
// EPI 1: v*=(*fscale); write bf16 into Cb (ld=ldcb)                 [read path]
// EPI 2: sigmoid(v+bias[col]); per-row sum -> atomicAdd rowsum[row] [gate path]
// EPI 3: write f32 C (out projection; gate scale + bias fused in LN)
template <int EPI>
__global__ __launch_bounds__(256)
void gemm_bt(const unsigned short* __restrict__ A, int lda,
             const unsigned short* __restrict__ Bt, int ldb,
             int Kd, int Nd,
             float* __restrict__ Cf,
             unsigned short* __restrict__ Cb, int ldcb,
             const float* __restrict__ bias,
             float* __restrict__ rowsum,
             const float* __restrict__ fscale)
{
  __shared__ unsigned short As[128 * 64];  // 16 KB
  __shared__ unsigned short Bs[64 * 64];   //  8 KB
  const int tid  = threadIdx.x;
  const int wid  = tid >> 6;
  const int lane = tid & 63;

  // T1 XCD swizzle (nwg % 8 == 0 for all our launches -> bijective)
  const int nwg  = gridDim.x * gridDim.y;
  const int flat = blockIdx.y * gridDim.x + blockIdx.x;
  const int swz  = (flat & 7) * (nwg >> 3) + (flat >> 3);
  const int bx   = swz % gridDim.x;
  const int by   = swz / gridDim.x;

  const int brow = by * 128;
  const int bcol = bx * 64;
  const int wr = wid >> 1, wc = wid & 1;
  const int l15 = lane & 15, l4 = lane >> 4;

  f32x4 acc[4][2] = {};

  const int foff = wid * 512 + lane * 8;  // flat bf16 element within 2048-elem chunk

  for (int k0 = 0; k0 < Kd; k0 += 64) {
#pragma unroll
    for (int c = 0; c < 4; ++c) {  // A: 128x64 = 8192 elems = 4 chunks
      int f = c * 2048 + foff;
      int r = f >> 6, kc = f & 63;
      gload_lds16(A + (size_t)(brow + r) * lda + k0 + kc, As + c * 2048 + wid * 512);
    }
#pragma unroll
    for (int c = 0; c < 2; ++c) {  // B: 64x64 = 4096 elems = 2 chunks
      int f = c * 2048 + foff;
      int r = f >> 6, kc = f & 63;
      gload_lds16(Bt + (size_t)(bcol + r) * ldb + k0 + kc, Bs + c * 2048 + wid * 512);
    }
    __syncthreads();   // compiler drains vmcnt before s_barrier
#pragma unroll
    for (int kk = 0; kk < 2; ++kk) {
      const int ko = kk * 32 + l4 * 8;
      bf16x8 af[4], bfv[2];
#pragma unroll
      for (int m = 0; m < 4; ++m)
        af[m] = *(const bf16x8*)(As + (wr * 64 + m * 16 + l15) * 64 + ko);
#pragma unroll
      for (int n = 0; n < 2; ++n)
        bfv[n] = *(const bf16x8*)(Bs + (wc * 32 + n * 16 + l15) * 64 + ko);
#pragma unroll
      for (int m = 0; m < 4; ++m)
#pragma unroll
        for (int n = 0; n < 2; ++n)
          acc[m][n] = __builtin_amdgcn_mfma_f32_16x16x32_bf16(af[m], bfv[n], acc[m][n], 0, 0, 0);
    }
    __syncthreads();
  }

  // C/D frag mapping (m89-verified): col = lane&15, row = (lane>>4)*4 + j
  if constexpr (EPI == 2) {
#pragma unroll
    for (int m = 0; m < 4; ++m) {
#pragma unroll
      for (int j = 0; j < 4; ++j) {
        float part = 0.0f;
#pragma unroll
        for (int n = 0; n < 2; ++n) {
          int col = bcol + wc * 32 + n * 16 + l15;
          float x = acc[m][n][j] + bias[col];
          part += 1.0f / (1.0f + __expf(-x));
        }
#pragma unroll
        for (int off = 1; off < 16; off <<= 1)
          part += __shfl_xor(part, off, 64);
        if (l15 == 0) {
          int row = brow + wr * 64 + m * 16 + l4 * 4 + j;
          atomicAdd(&rowsum[row], part);
        }
      }
    }
  } else {
    float fs = 1.0f;
    if constexpr (EPI == 1) fs = *fscale;
#pragma unroll
    for (int m = 0; m < 4; ++m) {
      int row0 = brow + wr * 64 + m * 16 + l4 * 4;
#pragma unroll
      for (int j = 0; j < 4; ++j) {
        int row = row0 + j;
#pragma unroll
        for (int n = 0; n < 2; ++n) {
          int col = bcol + wc * 32 + n * 16 + l15;
          float v = acc[m][n][j];
          if constexpr (EPI == 0) {
            Cf[(size_t)row * Nd + col] = v;
          } else if constexpr (EPI == 1) {
            Cb[(size_t)row * ldcb + col] = f2bf(v * fs);
          } else if constexpr (EPI == 3) {
            Cf[(size_t)row * Nd + col] = v;
          }
        }
      }
    }
  }
}

// ---------------- softmax over rows of 512: p = softmax(scores/sqrt(128) * w) -> bf16
__global__ __launch_bounds__(256)
void softmax_rows(const float* __restrict__ S, const float* __restrict__ W,
                  unsigned short* __restrict__ P)
{
  const int wid = threadIdx.x >> 6, lane = threadIdx.x & 63;
  const int row = blockIdx.x * 4 + wid;
  const size_t base = (size_t)row * 512 + lane * 8;
  const float sc = 0.08838834764831845f;  // 1/sqrt(128)
  f32x4 s0 = *(const f32x4*)(S + base);
  f32x4 s1 = *(const f32x4*)(S + base + 4);
  f32x4 w0 = *(const f32x4*)(W + base);
  f32x4 w1 = *(const f32x4*)(W + base + 4);
  float v[8];
#pragma unroll
  for (int i = 0; i < 4; ++i) { v[i] = s0[i] * sc * w0[i]; v[4 + i] = s1[i] * sc * w1[i]; }
  float mx = v[0];
#pragma unroll
  for (int i = 1; i < 8; ++i) mx = fmaxf(mx, v[i]);
#pragma unroll
  for (int off = 32; off >= 1; off >>= 1) mx = fmaxf(mx, __shfl_xor(mx, off, 64));
  float sum = 0.0f;
#pragma unroll
  for (int i = 0; i < 8; ++i) { v[i] = __expf(v[i] - mx); sum += v[i]; }
#pragma unroll
  for (int off = 32; off >= 1; off >>= 1) sum += __shfl_xor(sum, off, 64);
  const float inv = 1.0f / sum;
  union { unsigned short u[8]; i32x4 vec; } pk;
#pragma unroll
  for (int i = 0; i < 8; ++i) pk.u[i] = f2bf(v[i] * inv);
  *(i32x4*)(P + base) = pk.vec;
}

// ---------------- q -> qb (bf16) and upd -> cat[:, 1024:2048] (bf16), one launch
__global__ __launch_bounds__(256)
void cvt_q_upd(const float* __restrict__ q, const float* __restrict__ upd,
               unsigned short* __restrict__ qb, unsigned short* __restrict__ cat)
{
  int idx = blockIdx.x * 256 + threadIdx.x;  // 2097152 threads
  union { unsigned short u[8]; i32x4 vec; } pk;
  if (idx < 1048576) {
    size_t f = (size_t)idx * 8;
    f32x4 a = *(const f32x4*)(q + f);
    f32x4 b = *(const f32x4*)(q + f + 4);
#pragma unroll
    for (int i = 0; i < 4; ++i) { pk.u[i] = f2bf(a[i]); pk.u[4 + i] = f2bf(b[i]); }
    *(i32x4*)(qb + f) = pk.vec;
  } else {
    size_t f = (size_t)(idx - 1048576) * 8;
    int row = (int)(f >> 10);
    int col = (int)(f & 1023);
    f32x4 a = *(const f32x4*)(upd + f);
    f32x4 b = *(const f32x4*)(upd + f + 4);
#pragma unroll
    for (int i = 0; i < 4; ++i) { pk.u[i] = f2bf(a[i]); pk.u[4 + i] = f2bf(b[i]); }
    *(i32x4*)(cat + (size_t)row * 2048 + 1024 + col) = pk.vec;
  }
}

// ---------------- f32 -> bf16 convert (8 elems/thread), small inputs
__global__ __launch_bounds__(256)
void cvt_bf16x8(const float* __restrict__ in, unsigned short* __restrict__ out, int n8)
{
  int idx = blockIdx.x * 256 + threadIdx.x;
  if (idx >= n8) return;
  size_t f = (size_t)idx * 8;
  f32x4 a = *(const f32x4*)(in + f);
  f32x4 b = *(const f32x4*)(in + f + 4);
  union { unsigned short u[8]; i32x4 vec; } pk;
#pragma unroll
  for (int i = 0; i < 4; ++i) { pk.u[i] = f2bf(a[i]); pk.u[4 + i] = f2bf(b[i]); }
  *(i32x4*)(out + f) = pk.vec;
}

// ---------------- batched transpose f32[R,1024] -> bf16[1024,R] for gw/ow/mv
__global__ __launch_bounds__(256)
void transpose3(const float* __restrict__ gw, const float* __restrict__ ow,
                const float* __restrict__ mv,
                unsigned short* __restrict__ gwt, unsigned short* __restrict__ owt,
                unsigned short* __restrict__ vt)
{
  __shared__ float t[32][33];
  const int by = blockIdx.y;
  const float* in; unsigned short* out; int R, rb;
  if (by < 64)      { in = gw; out = gwt; R = 2048; rb = by; }
  else if (by < 96) { in = ow; out = owt; R = 1024; rb = by - 64; }
  else              { in = mv; out = vt;  R = 512;  rb = by - 96; }
  const int tx = threadIdx.x & 31, ty = threadIdx.x >> 5;
  const int c0 = blockIdx.x * 32, r0 = rb * 32;
#pragma unroll
  for (int i = 0; i < 4; ++i)
    t[ty + i * 8][tx] = in[(size_t)(r0 + ty + i * 8) * 1024 + c0 + tx];
  __syncthreads();
#pragma unroll
  for (int i = 0; i < 4; ++i)
    out[(size_t)(c0 + ty + i * 8) * R + r0 + tx] = f2bf(t[tx][ty + i * 8]);
}

// ---------------- LayerNorm over rows of 1024, block per row
// x = X[row]*(1 + gsum[row]/1024) + ob[col]  (gate scale + out bias fused here)
__global__ __launch_bounds__(256)
void ln_rows(const float* __restrict__ X, const float* __restrict__ gsum,
             const float* __restrict__ ob,
             const float* __restrict__ gamma, const float* __restrict__ beta,
             float* __restrict__ Y)
{
  const int row = blockIdx.x;
  const int tid = threadIdx.x;
  const size_t base = (size_t)row * 1024 + tid * 4;
  const float scl = 1.0f + gsum[row] * (1.0f / 1024.0f);
  f32x4 x = *(const f32x4*)(X + base);
  f32x4 bo = *(const f32x4*)(ob + tid * 4);
#pragma unroll
  for (int i = 0; i < 4; ++i) x[i] = x[i] * scl + bo[i];
  float s = x[0] + x[1] + x[2] + x[3];
  float q = x[0] * x[0] + x[1] * x[1] + x[2] * x[2] + x[3] * x[3];
#pragma unroll
  for (int off = 32; off >= 1; off >>= 1) {
    s += __shfl_xor(s, off, 64);
    q += __shfl_xor(q, off, 64);
  }
  __shared__ float ss[4], qq[4];
  const int wid = tid >> 6, lane = tid & 63;
  if (lane == 0) { ss[wid] = s; qq[wid] = q; }
  __syncthreads();
  s = ss[0] + ss[1] + ss[2] + ss[3];
  q = qq[0] + qq[1] + qq[2] + qq[3];
  const float mu = s * (1.0f / 1024.0f);
  const float var = q * (1.0f / 1024.0f) - mu * mu;
  const float r = rsqrtf(var + 1e-5f);
  f32x4 g = *(const f32x4*)(gamma + tid * 4);
  f32x4 b = *(const f32x4*)(beta + tid * 4);
  f32x4 y;
#pragma unroll
  for (int i = 0; i < 4; ++i) y[i] = (x[i] - mu) * r * g[i] + b[i];
  *(f32x4*)(Y + base) = y;
}

// ---------------- launch ----------------
extern "C" void kernel_launch(void* const* d_in, const int* in_sizes, int n_in,
                              void* d_out, int out_size, void* d_ws, size_t ws_size,
                              hipStream_t stream)
{
  (void)in_sizes; (void)n_in; (void)out_size; (void)ws_size;
  const float* q   = (const float*)d_in[0];   // [8192,1024]
  const float* mw  = (const float*)d_in[1];   // [8192,512]
  const float* upd = (const float*)d_in[2];   // [8192,1024]
  const float* mk  = (const float*)d_in[3];   // [512,1024]
  const float* mv  = (const float*)d_in[4];   // [512,1024]
  const float* dec = (const float*)d_in[5];   // scalar
  const float* gw  = (const float*)d_in[6];   // [2048,1024]
  const float* gb  = (const float*)d_in[7];   // [1024]
  const float* ow  = (const float*)d_in[8];   // [1024,1024]
  const float* ob  = (const float*)d_in[9];   // [1024]
  const float* lg  = (const float*)d_in[10];  // [1024]
  const float* lb  = (const float*)d_in[11];  // [1024]
  float* outp = (float*)d_out;
  char* ws = (char*)d_ws;

  // workspace layout (bytes); outpre overlays qb+scores after both are dead
  unsigned short* qb     = (unsigned short*)(ws + 0);          // 16.78 MB
  float*          scores = (float*)(ws + 16777216);            // 16.78 MB
  float*          outpre = (float*)(ws + 0);                   // 33.55 MB (reuse)
  unsigned short* kb     = (unsigned short*)(ws + 33554432);   // 1.05 MB
  unsigned short* vt     = (unsigned short*)(ws + 34603008);   // 1.05 MB
  unsigned short* gwt    = (unsigned short*)(ws + 35651584);   // 4.19 MB
  unsigned short* owt    = (unsigned short*)(ws + 39845888);   // 2.10 MB
  unsigned short* cat    = (unsigned short*)(ws + 41943040);   // 33.55 MB [8192,2048]
  unsigned short* probs  = (unsigned short*)(ws + 75497472);   // 8.39 MB
  float*          gsum   = (float*)(ws + 83886080);            // 32 KB
  // total ~84 MB

  // prep (3 launches)
  cvt_q_upd<<<8192, 256, 0, stream>>>(q, upd, qb, cat);
  cvt_bf16x8<<<256, 256, 0, stream>>>(mk, kb, 65536);
  transpose3<<<dim3(32, 112), 256, 0, stream>>>(gw, ow, mv, gwt, owt, vt);
  hipMemsetAsync(gsum, 0, 8192 * sizeof(float), stream);

  // 1) scores = qb x kb^T   [8192,512], K=1024  (512 blocks)
  gemm_bt<0><<<dim3(8, 64), 256, 0, stream>>>(qb, 1024, kb, 1024, 1024, 512,
                                              scores, nullptr, 0, nullptr, nullptr, nullptr);
  // 2) probs = softmax(scores/sqrt(128)*w) -> bf16
  softmax_rows<<<2048, 256, 0, stream>>>(scores, mw, probs);
  // 3) read = probs x vt^T * decay -> bf16 into cat[:, :1024]  (1024 blocks)
  gemm_bt<1><<<dim3(16, 64), 256, 0, stream>>>(probs, 512, vt, 512, 512, 1024,
                                               nullptr, cat, 2048, nullptr, nullptr, dec);
  // 4) gate rowsums: sigmoid(cat x gwt^T + gb) per-row sum -> gsum  (1024 blocks)
  gemm_bt<2><<<dim3(16, 64), 256, 0, stream>>>(cat, 2048, gwt, 2048, 2048, 1024,
                                               nullptr, nullptr, 0, gb, gsum, nullptr);
  // 5) outpre = read x owt^T  (raw; gate scale + bias fused into LN)  (1024 blocks)
  gemm_bt<3><<<dim3(16, 64), 256, 0, stream>>>(cat, 2048, owt, 1024, 1024, 1024,
                                               outpre, nullptr, 0, nullptr, nullptr, nullptr);
  // 6) LayerNorm (applies gate scale + out bias) -> final output
  ln_rows<<<8192, 256, 0, stream>>>(outpre, gsum, ob, lg, lb, outp);
}

// Round 5
// 115.737 us; speedup vs baseline: 1.6831x; 1.5048x over previous
//
#include <hip/hip_runtime.h>
#include <hip/hip_bf16.h>

typedef __attribute__((ext_vector_type(8))) short bf16x8;
typedef __attribute__((ext_vector_type(4))) float f32x4;
typedef __attribute__((ext_vector_type(4))) int i32x4;

// ---------- helpers ----------
static __device__ __forceinline__ void gload_lds16(const void* g, void* l) {
  __builtin_amdgcn_global_load_lds((const __attribute__((address_space(1))) void*)g,
                                   (__attribute__((address_space(3))) void*)l,
                                   16, 0, 0);
}

// f32 -> bf16 bits, round-to-nearest-even
static __device__ __forceinline__ unsigned short f2bf(float x) {
  unsigned int u = __float_as_uint(x);
  u += 0x7fffu + ((u >> 16) & 1u);
  return (unsigned short)(u >> 16);
}

// ---------------- flag = (max|out_b| != 0): gate path is LN-invariant iff out_b==0
__global__ __launch_bounds__(256)
void check_bias(const float* __restrict__ ob, int* __restrict__ flag)
{
  const int tid = threadIdx.x;
  f32x4 b = *(const f32x4*)(ob + tid * 4);
  float mx = fmaxf(fmaxf(fabsf(b[0]), fabsf(b[1])), fmaxf(fabsf(b[2]), fabsf(b[3])));
#pragma unroll
  for (int off = 32; off >= 1; off >>= 1) mx = fmaxf(mx, __shfl_xor(mx, off, 64));
  __shared__ float sm[4];
  const int wid = tid >> 6, lane = tid & 63;
  if (lane == 0) sm[wid] = mx;
  __syncthreads();
  if (tid == 0) {
    float m = fmaxf(fmaxf(sm[0], sm[1]), fmaxf(sm[2], sm[3]));
    *flag = (m != 0.0f) ? 1 : 0;
  }
}

// ---------------- GEMM: C[M,N] = A[M,K](bf16,row,lda) x Bt[N,K]^T(bf16,row,ldb)
// 128x64 tile, BK=64, 256 threads = 4 waves (2Mx2N), per-wave 64x32, acc[4][2].
// EPI 0: write f32 C (scores)
// EPI 1: v*=(*fscale); write bf16 into Cb (ld=ldcb)                 [read path]
// EPI 2: sigmoid(v+bias[col]); per-row sum -> atomicAdd rowsum[row] [gate path]
//        (skipped entirely when *flag==0: LN absorbs the per-row scale)
// EPI 3: write f32 C (out projection; gate scale + bias fused in LN)
template <int EPI>
__global__ __launch_bounds__(256)
void gemm_bt(const unsigned short* __restrict__ A, int lda,
             const unsigned short* __restrict__ Bt, int ldb,
             int Kd, int Nd,
             float* __restrict__ Cf,
             unsigned short* __restrict__ Cb, int ldcb,
             const float* __restrict__ bias,
             float* __restrict__ rowsum,
             const float* __restrict__ fscale,
             const int* __restrict__ flag)
{
  if constexpr (EPI == 2) {
    if (*flag == 0) return;  // out_b==0 -> gate scale cancels in LN
  }
  __shared__ unsigned short As[128 * 64];  // 16 KB
  __shared__ unsigned short Bs[64 * 64];   //  8 KB
  const int tid  = threadIdx.x;
  const int wid  = tid >> 6;
  const int lane = tid & 63;

  // T1 XCD swizzle (nwg % 8 == 0 for all our launches -> bijective)
  const int nwg  = gridDim.x * gridDim.y;
  const int flat = blockIdx.y * gridDim.x + blockIdx.x;
  const int swz  = (flat & 7) * (nwg >> 3) + (flat >> 3);
  const int bx   = swz % gridDim.x;
  const int by   = swz / gridDim.x;

  const int brow = by * 128;
  const int bcol = bx * 64;
  const int wr = wid >> 1, wc = wid & 1;
  const int l15 = lane & 15, l4 = lane >> 4;

  f32x4 acc[4][2] = {};

  const int foff = wid * 512 + lane * 8;  // flat bf16 element within 2048-elem chunk

  for (int k0 = 0; k0 < Kd; k0 += 64) {
#pragma unroll
    for (int c = 0; c < 4; ++c) {  // A: 128x64 = 8192 elems = 4 chunks
      int f = c * 2048 + foff;
      int r = f >> 6, kc = f & 63;
      gload_lds16(A + (size_t)(brow + r) * lda + k0 + kc, As + c * 2048 + wid * 512);
    }
#pragma unroll
    for (int c = 0; c < 2; ++c) {  // B: 64x64 = 4096 elems = 2 chunks
      int f = c * 2048 + foff;
      int r = f >> 6, kc = f & 63;
      gload_lds16(Bt + (size_t)(bcol + r) * ldb + k0 + kc, Bs + c * 2048 + wid * 512);
    }
    __syncthreads();   // compiler drains vmcnt before s_barrier
#pragma unroll
    for (int kk = 0; kk < 2; ++kk) {
      const int ko = kk * 32 + l4 * 8;
      bf16x8 af[4], bfv[2];
#pragma unroll
      for (int m = 0; m < 4; ++m)
        af[m] = *(const bf16x8*)(As + (wr * 64 + m * 16 + l15) * 64 + ko);
#pragma unroll
      for (int n = 0; n < 2; ++n)
        bfv[n] = *(const bf16x8*)(Bs + (wc * 32 + n * 16 + l15) * 64 + ko);
#pragma unroll
      for (int m = 0; m < 4; ++m)
#pragma unroll
        for (int n = 0; n < 2; ++n)
          acc[m][n] = __builtin_amdgcn_mfma_f32_16x16x32_bf16(af[m], bfv[n], acc[m][n], 0, 0, 0);
    }
    __syncthreads();
  }

  // C/D frag mapping (m89-verified): col = lane&15, row = (lane>>4)*4 + j
  if constexpr (EPI == 2) {
#pragma unroll
    for (int m = 0; m < 4; ++m) {
#pragma unroll
      for (int j = 0; j < 4; ++j) {
        float part = 0.0f;
#pragma unroll
        for (int n = 0; n < 2; ++n) {
          int col = bcol + wc * 32 + n * 16 + l15;
          float x = acc[m][n][j] + bias[col];
          part += 1.0f / (1.0f + __expf(-x));
        }
#pragma unroll
        for (int off = 1; off < 16; off <<= 1)
          part += __shfl_xor(part, off, 64);
        if (l15 == 0) {
          int row = brow + wr * 64 + m * 16 + l4 * 4 + j;
          atomicAdd(&rowsum[row], part);
        }
      }
    }
  } else {
    float fs = 1.0f;
    if constexpr (EPI == 1) fs = *fscale;
#pragma unroll
    for (int m = 0; m < 4; ++m) {
      int row0 = brow + wr * 64 + m * 16 + l4 * 4;
#pragma unroll
      for (int j = 0; j < 4; ++j) {
        int row = row0 + j;
#pragma unroll
        for (int n = 0; n < 2; ++n) {
          int col = bcol + wc * 32 + n * 16 + l15;
          float v = acc[m][n][j];
          if constexpr (EPI == 0) {
            Cf[(size_t)row * Nd + col] = v;
          } else if constexpr (EPI == 1) {
            Cb[(size_t)row * ldcb + col] = f2bf(v * fs);
          } else if constexpr (EPI == 3) {
            Cf[(size_t)row * Nd + col] = v;
          }
        }
      }
    }
  }
}

// ---------------- softmax over rows of 512: p = softmax(scores/sqrt(128) * w) -> bf16
__global__ __launch_bounds__(256)
void softmax_rows(const float* __restrict__ S, const float* __restrict__ W,
                  unsigned short* __restrict__ P)
{
  const int wid = threadIdx.x >> 6, lane = threadIdx.x & 63;
  const int row = blockIdx.x * 4 + wid;
  const size_t base = (size_t)row * 512 + lane * 8;
  const float sc = 0.08838834764831845f;  // 1/sqrt(128)
  f32x4 s0 = *(const f32x4*)(S + base);
  f32x4 s1 = *(const f32x4*)(S + base + 4);
  f32x4 w0 = *(const f32x4*)(W + base);
  f32x4 w1 = *(const f32x4*)(W + base + 4);
  float v[8];
#pragma unroll
  for (int i = 0; i < 4; ++i) { v[i] = s0[i] * sc * w0[i]; v[4 + i] = s1[i] * sc * w1[i]; }
  float mx = v[0];
#pragma unroll
  for (int i = 1; i < 8; ++i) mx = fmaxf(mx, v[i]);
#pragma unroll
  for (int off = 32; off >= 1; off >>= 1) mx = fmaxf(mx, __shfl_xor(mx, off, 64));
  float sum = 0.0f;
#pragma unroll
  for (int i = 0; i < 8; ++i) { v[i] = __expf(v[i] - mx); sum += v[i]; }
#pragma unroll
  for (int off = 32; off >= 1; off >>= 1) sum += __shfl_xor(sum, off, 64);
  const float inv = 1.0f / sum;
  union { unsigned short u[8]; i32x4 vec; } pk;
#pragma unroll
  for (int i = 0; i < 8; ++i) pk.u[i] = f2bf(v[i] * inv);
  *(i32x4*)(P + base) = pk.vec;
}

// ---------------- q -> qb (bf16); upd -> cat[:,1024:2048] only if *flag
__global__ __launch_bounds__(256)
void cvt_q_upd(const float* __restrict__ q, const float* __restrict__ upd,
               unsigned short* __restrict__ qb, unsigned short* __restrict__ cat,
               const int* __restrict__ flag)
{
  int idx = blockIdx.x * 256 + threadIdx.x;  // 2097152 threads
  union { unsigned short u[8]; i32x4 vec; } pk;
  if (idx < 1048576) {
    size_t f = (size_t)idx * 8;
    f32x4 a = *(const f32x4*)(q + f);
    f32x4 b = *(const f32x4*)(q + f + 4);
#pragma unroll
    for (int i = 0; i < 4; ++i) { pk.u[i] = f2bf(a[i]); pk.u[4 + i] = f2bf(b[i]); }
    *(i32x4*)(qb + f) = pk.vec;
  } else {
    if (*flag == 0) return;  // upd feeds only the gate path
    size_t f = (size_t)(idx - 1048576) * 8;
    int row = (int)(f >> 10);
    int col = (int)(f & 1023);
    f32x4 a = *(const f32x4*)(upd + f);
    f32x4 b = *(const f32x4*)(upd + f + 4);
#pragma unroll
    for (int i = 0; i < 4; ++i) { pk.u[i] = f2bf(a[i]); pk.u[4 + i] = f2bf(b[i]); }
    *(i32x4*)(cat + (size_t)row * 2048 + 1024 + col) = pk.vec;
  }
}

// ---------------- f32 -> bf16 convert (8 elems/thread), small inputs
__global__ __launch_bounds__(256)
void cvt_bf16x8(const float* __restrict__ in, unsigned short* __restrict__ out, int n8)
{
  int idx = blockIdx.x * 256 + threadIdx.x;
  if (idx >= n8) return;
  size_t f = (size_t)idx * 8;
  f32x4 a = *(const f32x4*)(in + f);
  f32x4 b = *(const f32x4*)(in + f + 4);
  union { unsigned short u[8]; i32x4 vec; } pk;
#pragma unroll
  for (int i = 0; i < 4; ++i) { pk.u[i] = f2bf(a[i]); pk.u[4 + i] = f2bf(b[i]); }
  *(i32x4*)(out + f) = pk.vec;
}

// ---------------- batched transpose f32[R,1024] -> bf16[1024,R] for gw/ow/mv
// gw part (gate weights) skipped when *flag==0
__global__ __launch_bounds__(256)
void transpose3(const float* __restrict__ gw, const float* __restrict__ ow,
                const float* __restrict__ mv,
                unsigned short* __restrict__ gwt, unsigned short* __restrict__ owt,
                unsigned short* __restrict__ vt,
                const int* __restrict__ flag)
{
  __shared__ float t[32][33];
  const int by = blockIdx.y;
  const float* in; unsigned short* out; int R, rb;
  if (by < 64) {
    if (*flag == 0) return;  // gate weights unused when gate path skipped
    in = gw; out = gwt; R = 2048; rb = by;
  }
  else if (by < 96) { in = ow; out = owt; R = 1024; rb = by - 64; }
  else              { in = mv; out = vt;  R = 512;  rb = by - 96; }
  const int tx = threadIdx.x & 31, ty = threadIdx.x >> 5;
  const int c0 = blockIdx.x * 32, r0 = rb * 32;
#pragma unroll
  for (int i = 0; i < 4; ++i)
    t[ty + i * 8][tx] = in[(size_t)(r0 + ty + i * 8) * 1024 + c0 + tx];
  __syncthreads();
#pragma unroll
  for (int i = 0; i < 4; ++i)
    out[(size_t)(c0 + ty + i * 8) * R + r0 + tx] = f2bf(t[tx][ty + i * 8]);
}

// ---------------- LayerNorm over rows of 1024, block per row
// x = X[row]*(1 + gsum[row]/1024) + ob[col]  (gate scale + out bias fused here)
// When the gate path is skipped, gsum stays memset-zero -> scl == 1 automatically.
__global__ __launch_bounds__(256)
void ln_rows(const float* __restrict__ X, const float* __restrict__ gsum,
             const float* __restrict__ ob,
             const float* __restrict__ gamma, const float* __restrict__ beta,
             float* __restrict__ Y)
{
  const int row = blockIdx.x;
  const int tid = threadIdx.x;
  const size_t base = (size_t)row * 1024 + tid * 4;
  const float scl = 1.0f + gsum[row] * (1.0f / 1024.0f);
  f32x4 x = *(const f32x4*)(X + base);
  f32x4 bo = *(const f32x4*)(ob + tid * 4);
#pragma unroll
  for (int i = 0; i < 4; ++i) x[i] = x[i] * scl + bo[i];
  float s = x[0] + x[1] + x[2] + x[3];
  float q = x[0] * x[0] + x[1] * x[1] + x[2] * x[2] + x[3] * x[3];
#pragma unroll
  for (int off = 32; off >= 1; off >>= 1) {
    s += __shfl_xor(s, off, 64);
    q += __shfl_xor(q, off, 64);
  }
  __shared__ float ss[4], qq[4];
  const int wid = tid >> 6, lane = tid & 63;
  if (lane == 0) { ss[wid] = s; qq[wid] = q; }
  __syncthreads();
  s = ss[0] + ss[1] + ss[2] + ss[3];
  q = qq[0] + qq[1] + qq[2] + qq[3];
  const float mu = s * (1.0f / 1024.0f);
  const float var = q * (1.0f / 1024.0f) - mu * mu;
  const float r = rsqrtf(var + 1e-5f);
  f32x4 g = *(const f32x4*)(gamma + tid * 4);
  f32x4 b = *(const f32x4*)(beta + tid * 4);
  f32x4 y;
#pragma unroll
  for (int i = 0; i < 4; ++i) y[i] = (x[i] - mu) * r * g[i] + b[i];
  *(f32x4*)(Y + base) = y;
}

// ---------------- launch ----------------
extern "C" void kernel_launch(void* const* d_in, const int* in_sizes, int n_in,
                              void* d_out, int out_size, void* d_ws, size_t ws_size,
                              hipStream_t stream)
{
  (void)in_sizes; (void)n_in; (void)out_size; (void)ws_size;
  const float* q   = (const float*)d_in[0];   // [8192,1024]
  const float* mw  = (const float*)d_in[1];   // [8192,512]
  const float* upd = (const float*)d_in[2];   // [8192,1024]
  const float* mk  = (const float*)d_in[3];   // [512,1024]
  const float* mv  = (const float*)d_in[4];   // [512,1024]
  const float* dec = (const float*)d_in[5];   // scalar
  const float* gw  = (const float*)d_in[6];   // [2048,1024]
  const float* gb  = (const float*)d_in[7];   // [1024]
  const float* ow  = (const float*)d_in[8];   // [1024,1024]
  const float* ob  = (const float*)d_in[9];   // [1024]
  const float* lg  = (const float*)d_in[10];  // [1024]
  const float* lb  = (const float*)d_in[11];  // [1024]
  float* outp = (float*)d_out;
  char* ws = (char*)d_ws;

  // workspace layout (bytes); outpre overlays qb+scores after both are dead
  unsigned short* qb     = (unsigned short*)(ws + 0);          // 16.78 MB
  float*          scores = (float*)(ws + 16777216);            // 16.78 MB
  float*          outpre = (float*)(ws + 0);                   // 33.55 MB (reuse)
  unsigned short* kb     = (unsigned short*)(ws + 33554432);   // 1.05 MB
  unsigned short* vt     = (unsigned short*)(ws + 34603008);   // 1.05 MB
  unsigned short* gwt    = (unsigned short*)(ws + 35651584);   // 4.19 MB
  unsigned short* owt    = (unsigned short*)(ws + 39845888);   // 2.10 MB
  unsigned short* cat    = (unsigned short*)(ws + 41943040);   // 33.55 MB [8192,2048]
  unsigned short* probs  = (unsigned short*)(ws + 75497472);   // 8.39 MB
  float*          gsum   = (float*)(ws + 83886080);            // 32 KB
  int*            flag   = (int*)(ws + 83918848);              // 4 B
  // total ~84 MB

  // 0) gate-path-needed flag (out_b != 0 ?)
  check_bias<<<1, 256, 0, stream>>>(ob, flag);
  hipMemsetAsync(gsum, 0, 8192 * sizeof(float), stream);

  // prep
  cvt_q_upd<<<8192, 256, 0, stream>>>(q, upd, qb, cat, flag);
  cvt_bf16x8<<<256, 256, 0, stream>>>(mk, kb, 65536);
  transpose3<<<dim3(32, 112), 256, 0, stream>>>(gw, ow, mv, gwt, owt, vt, flag);

  // 1) scores = qb x kb^T   [8192,512], K=1024  (512 blocks)
  gemm_bt<0><<<dim3(8, 64), 256, 0, stream>>>(qb, 1024, kb, 1024, 1024, 512,
                                              scores, nullptr, 0, nullptr, nullptr, nullptr, nullptr);
  // 2) probs = softmax(scores/sqrt(128)*w) -> bf16
  softmax_rows<<<2048, 256, 0, stream>>>(scores, mw, probs);
  // 3) read = probs x vt^T * decay -> bf16 into cat[:, :1024]  (1024 blocks)
  gemm_bt<1><<<dim3(16, 64), 256, 0, stream>>>(probs, 512, vt, 512, 512, 1024,
                                               nullptr, cat, 2048, nullptr, nullptr, dec, nullptr);
  // 4) gate rowsums (skipped when out_b==0: LN absorbs the per-row scale)
  gemm_bt<2><<<dim3(16, 64), 256, 0, stream>>>(cat, 2048, gwt, 2048, 2048, 1024,
                                               nullptr, nullptr, 0, gb, gsum, nullptr, flag);
  // 5) outpre = read x owt^T  (raw; gate scale + bias fused into LN)  (1024 blocks)
  gemm_bt<3><<<dim3(16, 64), 256, 0, stream>>>(cat, 2048, owt, 1024, 1024, 1024,
                                               outpre, nullptr, 0, nullptr, nullptr, nullptr, nullptr);
  // 6) LayerNorm (applies gate scale [=1 when skipped] + out bias) -> final output
  ln_rows<<<8192, 256, 0, stream>>>(outpre, gsum, ob, lg, lb, outp);
}

// Round 6
// 115.633 us; speedup vs baseline: 1.6846x; 1.0009x over previous
//
#include <hip/hip_runtime.h>
#include <hip/hip_bf16.h>

typedef __attribute__((ext_vector_type(8))) short bf16x8;
typedef __attribute__((ext_vector_type(4))) float f32x4;
typedef __attribute__((ext_vector_type(4))) int i32x4;

// ---------- helpers ----------
static __device__ __forceinline__ void gload_lds16(const void* g, void* l) {
  __builtin_amdgcn_global_load_lds((const __attribute__((address_space(1))) void*)g,
                                   (__attribute__((address_space(3))) void*)l,
                                   16, 0, 0);
}

// f32 -> bf16 bits, round-to-nearest-even
static __device__ __forceinline__ unsigned short f2bf(float x) {
  unsigned int u = __float_as_uint(x);
  u += 0x7fffu + ((u >> 16) & 1u);
  return (unsigned short)(u >> 16);
}

// ---------------- block 0: flag = (max|out_b| != 0); blocks 1..32: zero gsum
// (replaces the 40us graph-captured hipMemsetAsync fill)
__global__ __launch_bounds__(256)
void check_bias_zero(const float* __restrict__ ob, int* __restrict__ flag,
                     float* __restrict__ gsum)
{
  const int tid = threadIdx.x;
  if (blockIdx.x == 0) {
    f32x4 b = *(const f32x4*)(ob + tid * 4);
    float mx = fmaxf(fmaxf(fabsf(b[0]), fabsf(b[1])), fmaxf(fabsf(b[2]), fabsf(b[3])));
#pragma unroll
    for (int off = 32; off >= 1; off >>= 1) mx = fmaxf(mx, __shfl_xor(mx, off, 64));
    __shared__ float sm[4];
    const int wid = tid >> 6, lane = tid & 63;
    if (lane == 0) sm[wid] = mx;
    __syncthreads();
    if (tid == 0) {
      float m = fmaxf(fmaxf(sm[0], sm[1]), fmaxf(sm[2], sm[3]));
      *flag = (m != 0.0f) ? 1 : 0;
    }
  } else {
    gsum[(blockIdx.x - 1) * 256 + tid] = 0.0f;
  }
}

// ---------------- GEMM: C[M,N] = A[M,K](bf16,row,lda) x Bt[N,K]^T(bf16,row,ldb)
// 128x128 tile, BK=64, 256 threads = 4 waves (2x2), mfma_f32_16x16x32_bf16.
// (128x64 tile tried in R4: 518 TF vs this config's 568 TF -> reverted.)
// EPI 0: write f32 C (scores)
// EPI 1: v*=(*fscale); write bf16 into Cb (ld=ldcb)                 [read path]
// EPI 2: sigmoid(v+bias[col]); per-row sum -> atomicAdd rowsum[row] [gate path]
//        (skipped entirely when *flag==0: LN absorbs the per-row scale)
// EPI 3: write f32 C (out projection; gate scale + bias fused in LN)
template <int EPI>
__global__ __launch_bounds__(256)
void gemm_bt(const unsigned short* __restrict__ A, int lda,
             const unsigned short* __restrict__ Bt, int ldb,
             int Kd, int Nd,
             float* __restrict__ Cf,
             unsigned short* __restrict__ Cb, int ldcb,
             const float* __restrict__ bias,
             float* __restrict__ rowsum,
             const float* __restrict__ fscale,
             const int* __restrict__ flag)
{
  if constexpr (EPI == 2) {
    if (*flag == 0) return;  // out_b==0 -> gate scale cancels in LN
  }
  __shared__ unsigned short As[128 * 64];
  __shared__ unsigned short Bs[128 * 64];
  const int tid  = threadIdx.x;
  const int wid  = tid >> 6;
  const int lane = tid & 63;

  // T1 XCD swizzle (nwg % 8 == 0 for all our launches -> bijective)
  const int nwg  = gridDim.x * gridDim.y;
  const int flat = blockIdx.y * gridDim.x + blockIdx.x;
  const int swz  = (flat & 7) * (nwg >> 3) + (flat >> 3);
  const int bx   = swz % gridDim.x;
  const int by   = swz / gridDim.x;

  const int brow = by * 128;
  const int bcol = bx * 128;
  const int wr = wid >> 1, wc = wid & 1;
  const int l15 = lane & 15, l4 = lane >> 4;

  f32x4 acc[4][4] = {};

  const int foff = wid * 512 + lane * 8;  // flat bf16 element within 2048-elem chunk

  for (int k0 = 0; k0 < Kd; k0 += 64) {
#pragma unroll
    for (int c = 0; c < 4; ++c) {
      int f = c * 2048 + foff;
      int r = f >> 6, kc = f & 63;
      gload_lds16(A + (size_t)(brow + r) * lda + k0 + kc, As + c * 2048 + wid * 512);
    }
#pragma unroll
    for (int c = 0; c < 4; ++c) {
      int f = c * 2048 + foff;
      int r = f >> 6, kc = f & 63;
      gload_lds16(Bt + (size_t)(bcol + r) * ldb + k0 + kc, Bs + c * 2048 + wid * 512);
    }
    __syncthreads();   // compiler drains vmcnt before s_barrier
#pragma unroll
    for (int kk = 0; kk < 2; ++kk) {
      const int ko = kk * 32 + l4 * 8;
      bf16x8 af[4], bfv[4];
#pragma unroll
      for (int m = 0; m < 4; ++m)
        af[m] = *(const bf16x8*)(As + (wr * 64 + m * 16 + l15) * 64 + ko);
#pragma unroll
      for (int n = 0; n < 4; ++n)
        bfv[n] = *(const bf16x8*)(Bs + (wc * 64 + n * 16 + l15) * 64 + ko);
#pragma unroll
      for (int m = 0; m < 4; ++m)
#pragma unroll
        for (int n = 0; n < 4; ++n)
          acc[m][n] = __builtin_amdgcn_mfma_f32_16x16x32_bf16(af[m], bfv[n], acc[m][n], 0, 0, 0);
    }
    __syncthreads();
  }

  // C/D frag mapping (m89-verified): col = lane&15, row = (lane>>4)*4 + j
  if constexpr (EPI == 2) {
#pragma unroll
    for (int m = 0; m < 4; ++m) {
#pragma unroll
      for (int j = 0; j < 4; ++j) {
        float part = 0.0f;
#pragma unroll
        for (int n = 0; n < 4; ++n) {
          int col = bcol + wc * 64 + n * 16 + l15;
          float x = acc[m][n][j] + bias[col];
          part += 1.0f / (1.0f + __expf(-x));
        }
#pragma unroll
        for (int off = 1; off < 16; off <<= 1)
          part += __shfl_xor(part, off, 64);
        if (l15 == 0) {
          int row = brow + wr * 64 + m * 16 + l4 * 4 + j;
          atomicAdd(&rowsum[row], part);
        }
      }
    }
  } else {
    float fs = 1.0f;
    if constexpr (EPI == 1) fs = *fscale;
#pragma unroll
    for (int m = 0; m < 4; ++m) {
      int row0 = brow + wr * 64 + m * 16 + l4 * 4;
#pragma unroll
      for (int j = 0; j < 4; ++j) {
        int row = row0 + j;
#pragma unroll
        for (int n = 0; n < 4; ++n) {
          int col = bcol + wc * 64 + n * 16 + l15;
          float v = acc[m][n][j];
          if constexpr (EPI == 0) {
            Cf[(size_t)row * Nd + col] = v;
          } else if constexpr (EPI == 1) {
            Cb[(size_t)row * ldcb + col] = f2bf(v * fs);
          } else if constexpr (EPI == 3) {
            Cf[(size_t)row * Nd + col] = v;
          }
        }
      }
    }
  }
}

// ---------------- softmax over rows of 512: p = softmax(scores/sqrt(128) * w) -> bf16
__global__ __launch_bounds__(256)
void softmax_rows(const float* __restrict__ S, const float* __restrict__ W,
                  unsigned short* __restrict__ P)
{
  const int wid = threadIdx.x >> 6, lane = threadIdx.x & 63;
  const int row = blockIdx.x * 4 + wid;
  const size_t base = (size_t)row * 512 + lane * 8;
  const float sc = 0.08838834764831845f;  // 1/sqrt(128)
  f32x4 s0 = *(const f32x4*)(S + base);
  f32x4 s1 = *(const f32x4*)(S + base + 4);
  f32x4 w0 = *(const f32x4*)(W + base);
  f32x4 w1 = *(const f32x4*)(W + base + 4);
  float v[8];
#pragma unroll
  for (int i = 0; i < 4; ++i) { v[i] = s0[i] * sc * w0[i]; v[4 + i] = s1[i] * sc * w1[i]; }
  float mx = v[0];
#pragma unroll
  for (int i = 1; i < 8; ++i) mx = fmaxf(mx, v[i]);
#pragma unroll
  for (int off = 32; off >= 1; off >>= 1) mx = fmaxf(mx, __shfl_xor(mx, off, 64));
  float sum = 0.0f;
#pragma unroll
  for (int i = 0; i < 8; ++i) { v[i] = __expf(v[i] - mx); sum += v[i]; }
#pragma unroll
  for (int off = 32; off >= 1; off >>= 1) sum += __shfl_xor(sum, off, 64);
  const float inv = 1.0f / sum;
  union { unsigned short u[8]; i32x4 vec; } pk;
#pragma unroll
  for (int i = 0; i < 8; ++i) pk.u[i] = f2bf(v[i] * inv);
  *(i32x4*)(P + base) = pk.vec;
}

// ---------------- q -> qb (bf16); upd -> cat[:,1024:2048] only if *flag
__global__ __launch_bounds__(256)
void cvt_q_upd(const float* __restrict__ q, const float* __restrict__ upd,
               unsigned short* __restrict__ qb, unsigned short* __restrict__ cat,
               const int* __restrict__ flag)
{
  int idx = blockIdx.x * 256 + threadIdx.x;  // 2097152 threads
  union { unsigned short u[8]; i32x4 vec; } pk;
  if (idx < 1048576) {
    size_t f = (size_t)idx * 8;
    f32x4 a = *(const f32x4*)(q + f);
    f32x4 b = *(const f32x4*)(q + f + 4);
#pragma unroll
    for (int i = 0; i < 4; ++i) { pk.u[i] = f2bf(a[i]); pk.u[4 + i] = f2bf(b[i]); }
    *(i32x4*)(qb + f) = pk.vec;
  } else {
    if (*flag == 0) return;  // upd feeds only the gate path
    size_t f = (size_t)(idx - 1048576) * 8;
    int row = (int)(f >> 10);
    int col = (int)(f & 1023);
    f32x4 a = *(const f32x4*)(upd + f);
    f32x4 b = *(const f32x4*)(upd + f + 4);
#pragma unroll
    for (int i = 0; i < 4; ++i) { pk.u[i] = f2bf(a[i]); pk.u[4 + i] = f2bf(b[i]); }
    *(i32x4*)(cat + (size_t)row * 2048 + 1024 + col) = pk.vec;
  }
}

// ---------------- f32 -> bf16 convert (8 elems/thread), small inputs
__global__ __launch_bounds__(256)
void cvt_bf16x8(const float* __restrict__ in, unsigned short* __restrict__ out, int n8)
{
  int idx = blockIdx.x * 256 + threadIdx.x;
  if (idx >= n8) return;
  size_t f = (size_t)idx * 8;
  f32x4 a = *(const f32x4*)(in + f);
  f32x4 b = *(const f32x4*)(in + f + 4);
  union { unsigned short u[8]; i32x4 vec; } pk;
#pragma unroll
  for (int i = 0; i < 4; ++i) { pk.u[i] = f2bf(a[i]); pk.u[4 + i] = f2bf(b[i]); }
  *(i32x4*)(out + f) = pk.vec;
}

// ---------------- batched transpose f32[R,1024] -> bf16[1024,R] for gw/ow/mv
// gw part (gate weights) skipped when *flag==0
__global__ __launch_bounds__(256)
void transpose3(const float* __restrict__ gw, const float* __restrict__ ow,
                const float* __restrict__ mv,
                unsigned short* __restrict__ gwt, unsigned short* __restrict__ owt,
                unsigned short* __restrict__ vt,
                const int* __restrict__ flag)
{
  __shared__ float t[32][33];
  const int by = blockIdx.y;
  const float* in; unsigned short* out; int R, rb;
  if (by < 64) {
    if (*flag == 0) return;  // gate weights unused when gate path skipped
    in = gw; out = gwt; R = 2048; rb = by;
  }
  else if (by < 96) { in = ow; out = owt; R = 1024; rb = by - 64; }
  else              { in = mv; out = vt;  R = 512;  rb = by - 96; }
  const int tx = threadIdx.x & 31, ty = threadIdx.x >> 5;
  const int c0 = blockIdx.x * 32, r0 = rb * 32;
#pragma unroll
  for (int i = 0; i < 4; ++i)
    t[ty + i * 8][tx] = in[(size_t)(r0 + ty + i * 8) * 1024 + c0 + tx];
  __syncthreads();
#pragma unroll
  for (int i = 0; i < 4; ++i)
    out[(size_t)(c0 + ty + i * 8) * R + r0 + tx] = f2bf(t[tx][ty + i * 8]);
}

// ---------------- LayerNorm over rows of 1024, block per row
// x = X[row]*(1 + gsum[row]/1024) + ob[col]  (gate scale + out bias fused here)
// When the gate path is skipped, gsum is zeroed -> scl == 1 automatically.
__global__ __launch_bounds__(256)
void ln_rows(const float* __restrict__ X, const float* __restrict__ gsum,
             const float* __restrict__ ob,
             const float* __restrict__ gamma, const float* __restrict__ beta,
             float* __restrict__ Y)
{
  const int row = blockIdx.x;
  const int tid = threadIdx.x;
  const size_t base = (size_t)row * 1024 + tid * 4;
  const float scl = 1.0f + gsum[row] * (1.0f / 1024.0f);
  f32x4 x = *(const f32x4*)(X + base);
  f32x4 bo = *(const f32x4*)(ob + tid * 4);
#pragma unroll
  for (int i = 0; i < 4; ++i) x[i] = x[i] * scl + bo[i];
  float s = x[0] + x[1] + x[2] + x[3];
  float q = x[0] * x[0] + x[1] * x[1] + x[2] * x[2] + x[3] * x[3];
#pragma unroll
  for (int off = 32; off >= 1; off >>= 1) {
    s += __shfl_xor(s, off, 64);
    q += __shfl_xor(q, off, 64);
  }
  __shared__ float ss[4], qq[4];
  const int wid = tid >> 6, lane = tid & 63;
  if (lane == 0) { ss[wid] = s; qq[wid] = q; }
  __syncthreads();
  s = ss[0] + ss[1] + ss[2] + ss[3];
  q = qq[0] + qq[1] + qq[2] + qq[3];
  const float mu = s * (1.0f / 1024.0f);
  const float var = q * (1.0f / 1024.0f) - mu * mu;
  const float r = rsqrtf(var + 1e-5f);
  f32x4 g = *(const f32x4*)(gamma + tid * 4);
  f32x4 b = *(const f32x4*)(beta + tid * 4);
  f32x4 y;
#pragma unroll
  for (int i = 0; i < 4; ++i) y[i] = (x[i] - mu) * r * g[i] + b[i];
  *(f32x4*)(Y + base) = y;
}

// ---------------- launch ----------------
extern "C" void kernel_launch(void* const* d_in, const int* in_sizes, int n_in,
                              void* d_out, int out_size, void* d_ws, size_t ws_size,
                              hipStream_t stream)
{
  (void)in_sizes; (void)n_in; (void)out_size; (void)ws_size;
  const float* q   = (const float*)d_in[0];   // [8192,1024]
  const float* mw  = (const float*)d_in[1];   // [8192,512]
  const float* upd = (const float*)d_in[2];   // [8192,1024]
  const float* mk  = (const float*)d_in[3];   // [512,1024]
  const float* mv  = (const float*)d_in[4];   // [512,1024]
  const float* dec = (const float*)d_in[5];   // scalar
  const float* gw  = (const float*)d_in[6];   // [2048,1024]
  const float* gb  = (const float*)d_in[7];   // [1024]
  const float* ow  = (const float*)d_in[8];   // [1024,1024]
  const float* ob  = (const float*)d_in[9];   // [1024]
  const float* lg  = (const float*)d_in[10];  // [1024]
  const float* lb  = (const float*)d_in[11];  // [1024]
  float* outp = (float*)d_out;
  char* ws = (char*)d_ws;

  // workspace layout (bytes); outpre overlays qb+scores after both are dead
  unsigned short* qb     = (unsigned short*)(ws + 0);          // 16.78 MB
  float*          scores = (float*)(ws + 16777216);            // 16.78 MB
  float*          outpre = (float*)(ws + 0);                   // 33.55 MB (reuse)
  unsigned short* kb     = (unsigned short*)(ws + 33554432);   // 1.05 MB
  unsigned short* vt     = (unsigned short*)(ws + 34603008);   // 1.05 MB
  unsigned short* gwt    = (unsigned short*)(ws + 35651584);   // 4.19 MB
  unsigned short* owt    = (unsigned short*)(ws + 39845888);   // 2.10 MB
  unsigned short* cat    = (unsigned short*)(ws + 41943040);   // 33.55 MB [8192,2048]
  unsigned short* probs  = (unsigned short*)(ws + 75497472);   // 8.39 MB
  float*          gsum   = (float*)(ws + 83886080);            // 32 KB
  int*            flag   = (int*)(ws + 83918848);              // 4 B
  // total ~84 MB

  // 0) flag = (out_b != 0); zero gsum (replaces graph-captured memset)
  check_bias_zero<<<33, 256, 0, stream>>>(ob, flag, gsum);

  // prep
  cvt_q_upd<<<8192, 256, 0, stream>>>(q, upd, qb, cat, flag);
  cvt_bf16x8<<<256, 256, 0, stream>>>(mk, kb, 65536);
  transpose3<<<dim3(32, 112), 256, 0, stream>>>(gw, ow, mv, gwt, owt, vt, flag);

  // 1) scores = qb x kb^T   [8192,512], K=1024
  gemm_bt<0><<<dim3(4, 64), 256, 0, stream>>>(qb, 1024, kb, 1024, 1024, 512,
                                              scores, nullptr, 0, nullptr, nullptr, nullptr, nullptr);
  // 2) probs = softmax(scores/sqrt(128)*w) -> bf16
  softmax_rows<<<2048, 256, 0, stream>>>(scores, mw, probs);
  // 3) read = probs x vt^T * decay -> bf16 into cat[:, :1024]
  gemm_bt<1><<<dim3(8, 64), 256, 0, stream>>>(probs, 512, vt, 512, 512, 1024,
                                              nullptr, cat, 2048, nullptr, nullptr, dec, nullptr);
  // 4) gate rowsums (skipped when out_b==0: LN absorbs the per-row scale)
  gemm_bt<2><<<dim3(8, 64), 256, 0, stream>>>(cat, 2048, gwt, 2048, 2048, 1024,
                                              nullptr, nullptr, 0, gb, gsum, nullptr, flag);
  // 5) outpre = read x owt^T  (raw; gate scale + bias fused into LN)
  gemm_bt<3><<<dim3(8, 64), 256, 0, stream>>>(cat, 2048, owt, 1024, 1024, 1024,
                                              outpre, nullptr, 0, nullptr, nullptr, nullptr, nullptr);
  // 6) LayerNorm (applies gate scale [=1 when skipped] + out bias) -> final output
  ln_rows<<<8192, 256, 0, stream>>>(outpre, gsum, ob, lg, lb, outp);
}

// Round 7
// 110.160 us; speedup vs baseline: 1.7683x; 1.0497x over previous
//
#include <hip/hip_runtime.h>
#include <hip/hip_bf16.h>

typedef __attribute__((ext_vector_type(8))) short bf16x8;
typedef __attribute__((ext_vector_type(4))) float f32x4;
typedef __attribute__((ext_vector_type(4))) int i32x4;

// ---------- helpers ----------
static __device__ __forceinline__ void gload_lds16(const void* g, void* l) {
  __builtin_amdgcn_global_load_lds((const __attribute__((address_space(1))) void*)g,
                                   (__attribute__((address_space(3))) void*)l,
                                   16, 0, 0);
}

// f32 -> bf16 bits, round-to-nearest-even
static __device__ __forceinline__ unsigned short f2bf(float x) {
  unsigned int u = __float_as_uint(x);
  u += 0x7fffu + ((u >> 16) & 1u);
  return (unsigned short)(u >> 16);
}

// ---------------- block 0: flag = (max|out_b| != 0); blocks 1..32: zero gsum
__global__ __launch_bounds__(256)
void check_bias_zero(const float* __restrict__ ob, int* __restrict__ flag,
                     float* __restrict__ gsum)
{
  const int tid = threadIdx.x;
  if (blockIdx.x == 0) {
    f32x4 b = *(const f32x4*)(ob + tid * 4);
    float mx = fmaxf(fmaxf(fabsf(b[0]), fabsf(b[1])), fmaxf(fabsf(b[2]), fabsf(b[3])));
#pragma unroll
    for (int off = 32; off >= 1; off >>= 1) mx = fmaxf(mx, __shfl_xor(mx, off, 64));
    __shared__ float sm[4];
    const int wid = tid >> 6, lane = tid & 63;
    if (lane == 0) sm[wid] = mx;
    __syncthreads();
    if (tid == 0) {
      float m = fmaxf(fmaxf(sm[0], sm[1]), fmaxf(sm[2], sm[3]));
      *flag = (m != 0.0f) ? 1 : 0;
    }
  } else {
    gsum[(blockIdx.x - 1) * 256 + tid] = 0.0f;
  }
}

// ---------------- GEMM: C[M,N] = A[M,K](bf16,row,lda) x Bt[N,K]^T(bf16,row,ldb)
// 128xBN tile (BN=128 or 64), BK=64, 256 threads = 4 waves (2x2).
// If flag != nullptr and *flag == 0, the whole kernel is skipped.
// EPI 0: write f32 C (scores)
// EPI 1: v*=(*fscale); write bf16 into Cb (ld=ldcb)
// EPI 2: sigmoid(v+bias[col]); per-row sum -> atomicAdd rowsum[row]
// EPI 3: write f32 C
template <int EPI, int BN>
__global__ __launch_bounds__(256)
void gemm_bt(const unsigned short* __restrict__ A, int lda,
             const unsigned short* __restrict__ Bt, int ldb,
             int Kd, int Nd,
             float* __restrict__ Cf,
             unsigned short* __restrict__ Cb, int ldcb,
             const float* __restrict__ bias,
             float* __restrict__ rowsum,
             const float* __restrict__ fscale,
             const int* __restrict__ flag)
{
  if (flag != nullptr && *flag == 0) return;
  constexpr int NB = BN / 32;               // B chunks / acc N-count (128->4, 64->2)
  __shared__ unsigned short As[128 * 64];
  __shared__ unsigned short Bs[BN * 64];
  const int tid  = threadIdx.x;
  const int wid  = tid >> 6;
  const int lane = tid & 63;

  // T1 XCD swizzle (nwg % 8 == 0 for all our launches -> bijective)
  const int nwg  = gridDim.x * gridDim.y;
  const int flat = blockIdx.y * gridDim.x + blockIdx.x;
  const int swz  = (flat & 7) * (nwg >> 3) + (flat >> 3);
  const int bx   = swz % gridDim.x;
  const int by   = swz / gridDim.x;

  const int brow = by * 128;
  const int bcol = bx * BN;
  const int wr = wid >> 1, wc = wid & 1;
  const int l15 = lane & 15, l4 = lane >> 4;

  f32x4 acc[4][NB] = {};

  const int foff = wid * 512 + lane * 8;  // flat bf16 element within 2048-elem chunk

  for (int k0 = 0; k0 < Kd; k0 += 64) {
#pragma unroll
    for (int c = 0; c < 4; ++c) {   // A: 128x64 = 4 chunks
      int f = c * 2048 + foff;
      int r = f >> 6, kc = f & 63;
      gload_lds16(A + (size_t)(brow + r) * lda + k0 + kc, As + c * 2048 + wid * 512);
    }
#pragma unroll
    for (int c = 0; c < NB; ++c) {  // B: BNx64 = NB chunks
      int f = c * 2048 + foff;
      int r = f >> 6, kc = f & 63;
      gload_lds16(Bt + (size_t)(bcol + r) * ldb + k0 + kc, Bs + c * 2048 + wid * 512);
    }
    __syncthreads();
#pragma unroll
    for (int kk = 0; kk < 2; ++kk) {
      const int ko = kk * 32 + l4 * 8;
      bf16x8 af[4], bfv[NB];
#pragma unroll
      for (int m = 0; m < 4; ++m)
        af[m] = *(const bf16x8*)(As + (wr * 64 + m * 16 + l15) * 64 + ko);
#pragma unroll
      for (int n = 0; n < NB; ++n)
        bfv[n] = *(const bf16x8*)(Bs + (wc * (BN / 2) + n * 16 + l15) * 64 + ko);
#pragma unroll
      for (int m = 0; m < 4; ++m)
#pragma unroll
        for (int n = 0; n < NB; ++n)
          acc[m][n] = __builtin_amdgcn_mfma_f32_16x16x32_bf16(af[m], bfv[n], acc[m][n], 0, 0, 0);
    }
    __syncthreads();
  }

  // C/D frag mapping (m89-verified): col = lane&15, row = (lane>>4)*4 + j
  if constexpr (EPI == 2) {
#pragma unroll
    for (int m = 0; m < 4; ++m) {
#pragma unroll
      for (int j = 0; j < 4; ++j) {
        float part = 0.0f;
#pragma unroll
        for (int n = 0; n < NB; ++n) {
          int col = bcol + wc * (BN / 2) + n * 16 + l15;
          float x = acc[m][n][j] + bias[col];
          part += 1.0f / (1.0f + __expf(-x));
        }
#pragma unroll
        for (int off = 1; off < 16; off <<= 1)
          part += __shfl_xor(part, off, 64);
        if (l15 == 0) {
          int row = brow + wr * 64 + m * 16 + l4 * 4 + j;
          atomicAdd(&rowsum[row], part);
        }
      }
    }
  } else {
    float fs = 1.0f;
    if constexpr (EPI == 1) fs = *fscale;
#pragma unroll
    for (int m = 0; m < 4; ++m) {
      int row0 = brow + wr * 64 + m * 16 + l4 * 4;
#pragma unroll
      for (int j = 0; j < 4; ++j) {
        int row = row0 + j;
#pragma unroll
        for (int n = 0; n < NB; ++n) {
          int col = bcol + wc * (BN / 2) + n * 16 + l15;
          float v = acc[m][n][j];
          if constexpr (EPI == 0) {
            Cf[(size_t)row * Nd + col] = v;
          } else if constexpr (EPI == 1) {
            Cb[(size_t)row * ldcb + col] = f2bf(v * fs);
          } else if constexpr (EPI == 3) {
            Cf[(size_t)row * Nd + col] = v;
          }
        }
      }
    }
  }
}

// ---------------- softmax over rows of 512: p = softmax(scores/sqrt(128) * w) -> bf16
__global__ __launch_bounds__(256)
void softmax_rows(const float* __restrict__ S, const float* __restrict__ W,
                  unsigned short* __restrict__ P)
{
  const int wid = threadIdx.x >> 6, lane = threadIdx.x & 63;
  const int row = blockIdx.x * 4 + wid;
  const size_t base = (size_t)row * 512 + lane * 8;
  const float sc = 0.08838834764831845f;  // 1/sqrt(128)
  f32x4 s0 = *(const f32x4*)(S + base);
  f32x4 s1 = *(const f32x4*)(S + base + 4);
  f32x4 w0 = *(const f32x4*)(W + base);
  f32x4 w1 = *(const f32x4*)(W + base + 4);
  float v[8];
#pragma unroll
  for (int i = 0; i < 4; ++i) { v[i] = s0[i] * sc * w0[i]; v[4 + i] = s1[i] * sc * w1[i]; }
  float mx = v[0];
#pragma unroll
  for (int i = 1; i < 8; ++i) mx = fmaxf(mx, v[i]);
#pragma unroll
  for (int off = 32; off >= 1; off >>= 1) mx = fmaxf(mx, __shfl_xor(mx, off, 64));
  float sum = 0.0f;
#pragma unroll
  for (int i = 0; i < 8; ++i) { v[i] = __expf(v[i] - mx); sum += v[i]; }
#pragma unroll
  for (int off = 32; off >= 1; off >>= 1) sum += __shfl_xor(sum, off, 64);
  const float inv = 1.0f / sum;
  union { unsigned short u[8]; i32x4 vec; } pk;
#pragma unroll
  for (int i = 0; i < 8; ++i) pk.u[i] = f2bf(v[i] * inv);
  *(i32x4*)(P + base) = pk.vec;
}

// ---------------- q -> qb (bf16); upd -> cat[:,1024:2048] only if *flag
__global__ __launch_bounds__(256)
void cvt_q_upd(const float* __restrict__ q, const float* __restrict__ upd,
               unsigned short* __restrict__ qb, unsigned short* __restrict__ cat,
               const int* __restrict__ flag)
{
  int idx = blockIdx.x * 256 + threadIdx.x;  // 2097152 threads
  union { unsigned short u[8]; i32x4 vec; } pk;
  if (idx < 1048576) {
    size_t f = (size_t)idx * 8;
    f32x4 a = *(const f32x4*)(q + f);
    f32x4 b = *(const f32x4*)(q + f + 4);
#pragma unroll
    for (int i = 0; i < 4; ++i) { pk.u[i] = f2bf(a[i]); pk.u[4 + i] = f2bf(b[i]); }
    *(i32x4*)(qb + f) = pk.vec;
  } else {
    if (*flag == 0) return;  // upd feeds only the gate path
    size_t f = (size_t)(idx - 1048576) * 8;
    int row = (int)(f >> 10);
    int col = (int)(f & 1023);
    f32x4 a = *(const f32x4*)(upd + f);
    f32x4 b = *(const f32x4*)(upd + f + 4);
#pragma unroll
    for (int i = 0; i < 4; ++i) { pk.u[i] = f2bf(a[i]); pk.u[4 + i] = f2bf(b[i]); }
    *(i32x4*)(cat + (size_t)row * 2048 + 1024 + col) = pk.vec;
  }
}

// ---------------- f32 -> bf16 convert (8 elems/thread)
__global__ __launch_bounds__(256)
void cvt_bf16x8(const float* __restrict__ in, unsigned short* __restrict__ out, int n8)
{
  int idx = blockIdx.x * 256 + threadIdx.x;
  if (idx >= n8) return;
  size_t f = (size_t)idx * 8;
  f32x4 a = *(const f32x4*)(in + f);
  f32x4 b = *(const f32x4*)(in + f + 4);
  union { unsigned short u[8]; i32x4 vec; } pk;
#pragma unroll
  for (int i = 0; i < 4; ++i) { pk.u[i] = f2bf(a[i]); pk.u[4 + i] = f2bf(b[i]); }
  *(i32x4*)(out + f) = pk.vec;
}

// ---------------- batched transpose f32[R,1024] -> bf16[1024,R]
// gw and mv parts only needed for the gate path (flag==1); ow always.
__global__ __launch_bounds__(256)
void transpose3(const float* __restrict__ gw, const float* __restrict__ ow,
                const float* __restrict__ mv,
                unsigned short* __restrict__ gwt, unsigned short* __restrict__ owt,
                unsigned short* __restrict__ vt,
                const int* __restrict__ flag)
{
  __shared__ float t[32][33];
  const int by = blockIdx.y;
  const float* in; unsigned short* out; int R, rb;
  if (by < 64) {
    if (*flag == 0) return;  // gate weights unused when gate path skipped
    in = gw; out = gwt; R = 2048; rb = by;
  }
  else if (by < 96) { in = ow; out = owt; R = 1024; rb = by - 64; }
  else {
    if (*flag == 0) return;  // vt only feeds the read-materialization (gate) path
    in = mv; out = vt;  R = 512;  rb = by - 96;
  }
  const int tx = threadIdx.x & 31, ty = threadIdx.x >> 5;
  const int c0 = blockIdx.x * 32, r0 = rb * 32;
#pragma unroll
  for (int i = 0; i < 4; ++i)
    t[ty + i * 8][tx] = in[(size_t)(r0 + ty + i * 8) * 1024 + c0 + tx];
  __syncthreads();
#pragma unroll
  for (int i = 0; i < 4; ++i)
    out[(size_t)(c0 + ty + i * 8) * R + r0 + tx] = f2bf(t[tx][ty + i * 8]);
}

// ---------------- LayerNorm over rows of 1024, block per row
// x = X[row]*(1 + gsum[row]/1024) + ob[col]; gsum==0 when gate path skipped.
__global__ __launch_bounds__(256)
void ln_rows(const float* __restrict__ X, const float* __restrict__ gsum,
             const float* __restrict__ ob,
             const float* __restrict__ gamma, const float* __restrict__ beta,
             float* __restrict__ Y)
{
  const int row = blockIdx.x;
  const int tid = threadIdx.x;
  const size_t base = (size_t)row * 1024 + tid * 4;
  const float scl = 1.0f + gsum[row] * (1.0f / 1024.0f);
  f32x4 x = *(const f32x4*)(X + base);
  f32x4 bo = *(const f32x4*)(ob + tid * 4);
#pragma unroll
  for (int i = 0; i < 4; ++i) x[i] = x[i] * scl + bo[i];
  float s = x[0] + x[1] + x[2] + x[3];
  float q = x[0] * x[0] + x[1] * x[1] + x[2] * x[2] + x[3] * x[3];
#pragma unroll
  for (int off = 32; off >= 1; off >>= 1) {
    s += __shfl_xor(s, off, 64);
    q += __shfl_xor(q, off, 64);
  }
  __shared__ float ss[4], qq[4];
  const int wid = tid >> 6, lane = tid & 63;
  if (lane == 0) { ss[wid] = s; qq[wid] = q; }
  __syncthreads();
  s = ss[0] + ss[1] + ss[2] + ss[3];
  q = qq[0] + qq[1] + qq[2] + qq[3];
  const float mu = s * (1.0f / 1024.0f);
  const float var = q * (1.0f / 1024.0f) - mu * mu;
  const float r = rsqrtf(var + 1e-5f);
  f32x4 g = *(const f32x4*)(gamma + tid * 4);
  f32x4 b = *(const f32x4*)(beta + tid * 4);
  f32x4 y;
#pragma unroll
  for (int i = 0; i < 4; ++i) y[i] = (x[i] - mu) * r * g[i] + b[i];
  *(f32x4*)(Y + base) = y;
}

// ---------------- launch ----------------
extern "C" void kernel_launch(void* const* d_in, const int* in_sizes, int n_in,
                              void* d_out, int out_size, void* d_ws, size_t ws_size,
                              hipStream_t stream)
{
  (void)in_sizes; (void)n_in; (void)out_size; (void)ws_size;
  const float* q   = (const float*)d_in[0];   // [8192,1024]
  const float* mw  = (const float*)d_in[1];   // [8192,512]
  const float* upd = (const float*)d_in[2];   // [8192,1024]
  const float* mk  = (const float*)d_in[3];   // [512,1024]
  const float* mv  = (const float*)d_in[4];   // [512,1024]
  const float* dec = (const float*)d_in[5];   // scalar
  const float* gw  = (const float*)d_in[6];   // [2048,1024]
  const float* gb  = (const float*)d_in[7];   // [1024]
  const float* ow  = (const float*)d_in[8];   // [1024,1024]
  const float* ob  = (const float*)d_in[9];   // [1024]
  const float* lg  = (const float*)d_in[10];  // [1024]
  const float* lb  = (const float*)d_in[11];  // [1024]
  float* outp = (float*)d_out;
  char* ws = (char*)d_ws;

  // workspace layout (bytes); outpre overlays qb+scores after both are dead
  unsigned short* qb     = (unsigned short*)(ws + 0);          // 16.78 MB
  float*          scores = (float*)(ws + 16777216);            // 16.78 MB
  float*          outpre = (float*)(ws + 0);                   // 33.55 MB (reuse)
  unsigned short* kb     = (unsigned short*)(ws + 33554432);   // 1.05 MB
  unsigned short* vt     = (unsigned short*)(ws + 34603008);   // 1.05 MB
  unsigned short* gwt    = (unsigned short*)(ws + 35651584);   // 4.19 MB
  unsigned short* owt    = (unsigned short*)(ws + 39845888);   // 2.10 MB
  unsigned short* cat    = (unsigned short*)(ws + 41943040);   // 33.55 MB [8192,2048]
  unsigned short* probs  = (unsigned short*)(ws + 75497472);   // 8.39 MB
  float*          gsum   = (float*)(ws + 83886080);            // 32 KB
  int*            flag   = (int*)(ws + 83918848);              // 4 B
  unsigned short* mvb    = (unsigned short*)(ws + 84934656);   // 1.05 MB [512,1024] bf16
  unsigned short* w2t    = (unsigned short*)(ws + 85983232);   // 1.05 MB [1024,512] bf16
  // total ~87 MB

  // 0) flag = (out_b != 0); zero gsum
  check_bias_zero<<<33, 256, 0, stream>>>(ob, flag, gsum);

  // prep
  cvt_q_upd<<<8192, 256, 0, stream>>>(q, upd, qb, cat, flag);
  cvt_bf16x8<<<256, 256, 0, stream>>>(mk, kb, 65536);
  cvt_bf16x8<<<256, 256, 0, stream>>>(mv, mvb, 65536);
  transpose3<<<dim3(32, 112), 256, 0, stream>>>(gw, ow, mv, gwt, owt, vt, flag);

  // 1) scores = qb x kb^T  [8192,512], K=1024  (BN=64 tile -> 512 blocks, 2/CU)
  gemm_bt<0, 64><<<dim3(8, 64), 256, 0, stream>>>(qb, 1024, kb, 1024, 1024, 512,
                                                  scores, nullptr, 0, nullptr, nullptr, nullptr, nullptr);
  // 2) probs = softmax(scores/sqrt(128)*w) -> bf16
  softmax_rows<<<2048, 256, 0, stream>>>(scores, mw, probs);
  // 3) w2t = (decay*mv @ ow)^T = owt x mvb^T * decay  [1024,512] bf16  (32 blocks, 1.1 GF)
  gemm_bt<1, 128><<<dim3(4, 8), 256, 0, stream>>>(owt, 1024, mvb, 1024, 1024, 512,
                                                  nullptr, w2t, 512, nullptr, nullptr, dec, nullptr);
  // 4) [flag only] read = probs x vt^T * decay -> bf16 into cat[:, :1024]
  gemm_bt<1, 128><<<dim3(8, 64), 256, 0, stream>>>(probs, 512, vt, 512, 512, 1024,
                                                   nullptr, cat, 2048, nullptr, nullptr, dec, flag);
  // 5) [flag only] gate rowsums: sigmoid(cat x gwt^T + gb) -> gsum
  gemm_bt<2, 128><<<dim3(8, 64), 256, 0, stream>>>(cat, 2048, gwt, 2048, 2048, 1024,
                                                   nullptr, nullptr, 0, gb, gsum, nullptr, flag);
  // 6) outpre = probs x w2t^T  ( = (P@V')@ow by associativity )  [8192,1024], K=512
  gemm_bt<3, 128><<<dim3(8, 64), 256, 0, stream>>>(probs, 512, w2t, 512, 512, 1024,
                                                   outpre, nullptr, 0, nullptr, nullptr, nullptr, nullptr);
  // 7) LayerNorm (applies gate scale [=1 when skipped] + out bias) -> final output
  ln_rows<<<8192, 256, 0, stream>>>(outpre, gsum, ob, lg, lb, outp);
}

// Round 8
// 97.504 us; speedup vs baseline: 1.9978x; 1.1298x over previous
//
#include <hip/hip_runtime.h>
#include <hip/hip_bf16.h>

typedef __attribute__((ext_vector_type(8))) short bf16x8;
typedef __attribute__((ext_vector_type(4))) float f32x4;
typedef __attribute__((ext_vector_type(4))) int i32x4;
typedef __attribute__((ext_vector_type(2))) int i32x2;

// ---------- helpers ----------
static __device__ __forceinline__ void gload_lds16(const void* g, void* l) {
  __builtin_amdgcn_global_load_lds((const __attribute__((address_space(1))) void*)g,
                                   (__attribute__((address_space(3))) void*)l,
                                   16, 0, 0);
}

// f32 -> bf16 bits, round-to-nearest-even
static __device__ __forceinline__ unsigned short f2bf(float x) {
  unsigned int u = __float_as_uint(x);
  u += 0x7fffu + ((u >> 16) & 1u);
  return (unsigned short)(u >> 16);
}

// ---------------- block 0: flag = (max|out_b| != 0); blocks 1..32: zero gsum
__global__ __launch_bounds__(256)
void check_bias_zero(const float* __restrict__ ob, int* __restrict__ flag,
                     float* __restrict__ gsum)
{
  const int tid = threadIdx.x;
  if (blockIdx.x == 0) {
    f32x4 b = *(const f32x4*)(ob + tid * 4);
    float mx = fmaxf(fmaxf(fabsf(b[0]), fabsf(b[1])), fmaxf(fabsf(b[2]), fabsf(b[3])));
#pragma unroll
    for (int off = 32; off >= 1; off >>= 1) mx = fmaxf(mx, __shfl_xor(mx, off, 64));
    __shared__ float sm[4];
    const int wid = tid >> 6, lane = tid & 63;
    if (lane == 0) sm[wid] = mx;
    __syncthreads();
    if (tid == 0) {
      float m = fmaxf(fmaxf(sm[0], sm[1]), fmaxf(sm[2], sm[3]));
      *flag = (m != 0.0f) ? 1 : 0;
    }
  } else {
    gsum[(blockIdx.x - 1) * 256 + tid] = 0.0f;
  }
}

// ---------------- GEMM: C[M,N] = A[M,K](bf16,row,lda) x Bt[N,K]^T(bf16,row,ldb)
// 128xBN tile (BN=128 or 64), BK=64, 256 threads = 4 waves (2x2).
// If flag != nullptr and *flag == 0, the whole kernel is skipped.
// EPI 1: v*=(*fscale); write bf16 into Cb (ld=ldcb)
// EPI 2: sigmoid(v+bias[col]); per-row sum -> atomicAdd rowsum[row]
// EPI 3: write f32 C
// EPI 4: write f32 C = v * (1/sqrt(128)) * bias[row*Nd+col]  [scores: mw fused]
template <int EPI, int BN>
__global__ __launch_bounds__(256)
void gemm_bt(const unsigned short* __restrict__ A, int lda,
             const unsigned short* __restrict__ Bt, int ldb,
             int Kd, int Nd,
             float* __restrict__ Cf,
             unsigned short* __restrict__ Cb, int ldcb,
             const float* __restrict__ bias,
             float* __restrict__ rowsum,
             const float* __restrict__ fscale,
             const int* __restrict__ flag)
{
  if (flag != nullptr && *flag == 0) return;
  constexpr int NB = BN / 32;               // B chunks / acc N-count (128->4, 64->2)
  __shared__ unsigned short As[128 * 64];
  __shared__ unsigned short Bs[BN * 64];
  const int tid  = threadIdx.x;
  const int wid  = tid >> 6;
  const int lane = tid & 63;

  // T1 XCD swizzle (nwg % 8 == 0 for all our launches -> bijective)
  const int nwg  = gridDim.x * gridDim.y;
  const int flat = blockIdx.y * gridDim.x + blockIdx.x;
  const int swz  = (flat & 7) * (nwg >> 3) + (flat >> 3);
  const int bx   = swz % gridDim.x;
  const int by   = swz / gridDim.x;

  const int brow = by * 128;
  const int bcol = bx * BN;
  const int wr = wid >> 1, wc = wid & 1;
  const int l15 = lane & 15, l4 = lane >> 4;

  f32x4 acc[4][NB] = {};

  const int foff = wid * 512 + lane * 8;  // flat bf16 element within 2048-elem chunk

  for (int k0 = 0; k0 < Kd; k0 += 64) {
#pragma unroll
    for (int c = 0; c < 4; ++c) {   // A: 128x64 = 4 chunks
      int f = c * 2048 + foff;
      int r = f >> 6, kc = f & 63;
      gload_lds16(A + (size_t)(brow + r) * lda + k0 + kc, As + c * 2048 + wid * 512);
    }
#pragma unroll
    for (int c = 0; c < NB; ++c) {  // B: BNx64 = NB chunks
      int f = c * 2048 + foff;
      int r = f >> 6, kc = f & 63;
      gload_lds16(Bt + (size_t)(bcol + r) * ldb + k0 + kc, Bs + c * 2048 + wid * 512);
    }
    __syncthreads();
#pragma unroll
    for (int kk = 0; kk < 2; ++kk) {
      const int ko = kk * 32 + l4 * 8;
      bf16x8 af[4], bfv[NB];
#pragma unroll
      for (int m = 0; m < 4; ++m)
        af[m] = *(const bf16x8*)(As + (wr * 64 + m * 16 + l15) * 64 + ko);
#pragma unroll
      for (int n = 0; n < NB; ++n)
        bfv[n] = *(const bf16x8*)(Bs + (wc * (BN / 2) + n * 16 + l15) * 64 + ko);
#pragma unroll
      for (int m = 0; m < 4; ++m)
#pragma unroll
        for (int n = 0; n < NB; ++n)
          acc[m][n] = __builtin_amdgcn_mfma_f32_16x16x32_bf16(af[m], bfv[n], acc[m][n], 0, 0, 0);
    }
    __syncthreads();
  }

  // C/D frag mapping (m89-verified): col = lane&15, row = (lane>>4)*4 + j
  if constexpr (EPI == 2) {
#pragma unroll
    for (int m = 0; m < 4; ++m) {
#pragma unroll
      for (int j = 0; j < 4; ++j) {
        float part = 0.0f;
#pragma unroll
        for (int n = 0; n < NB; ++n) {
          int col = bcol + wc * (BN / 2) + n * 16 + l15;
          float x = acc[m][n][j] + bias[col];
          part += 1.0f / (1.0f + __expf(-x));
        }
#pragma unroll
        for (int off = 1; off < 16; off <<= 1)
          part += __shfl_xor(part, off, 64);
        if (l15 == 0) {
          int row = brow + wr * 64 + m * 16 + l4 * 4 + j;
          atomicAdd(&rowsum[row], part);
        }
      }
    }
  } else {
    float fs = 1.0f;
    if constexpr (EPI == 1) fs = *fscale;
#pragma unroll
    for (int m = 0; m < 4; ++m) {
      int row0 = brow + wr * 64 + m * 16 + l4 * 4;
#pragma unroll
      for (int j = 0; j < 4; ++j) {
        int row = row0 + j;
#pragma unroll
        for (int n = 0; n < NB; ++n) {
          int col = bcol + wc * (BN / 2) + n * 16 + l15;
          float v = acc[m][n][j];
          if constexpr (EPI == 1) {
            Cb[(size_t)row * ldcb + col] = f2bf(v * fs);
          } else if constexpr (EPI == 3) {
            Cf[(size_t)row * Nd + col] = v;
          } else if constexpr (EPI == 4) {
            // scores: scale + multiplicative mask fused (same op order as before)
            Cf[(size_t)row * Nd + col] =
                v * 0.08838834764831845f * bias[(size_t)row * Nd + col];
          }
        }
      }
    }
  }
}

// ---------------- w2 split-K partial: w2p[s] += owt[128r x 64k] x mvb[128c x 64k]^T
// grid (4, 8, 8): x -> N=512 col tiles (mvb rows), y -> M=1024 row tiles (owt
// rows), z -> K-slice of 128. Full-machine 256 blocks (vs 32 single-level).
__global__ __launch_bounds__(256)
void w2_partial(const unsigned short* __restrict__ owt,
                const unsigned short* __restrict__ mvb,
                float* __restrict__ w2p)
{
  __shared__ unsigned short As[128 * 64];
  __shared__ unsigned short Bs[128 * 64];
  const int tid  = threadIdx.x;
  const int wid  = tid >> 6;
  const int lane = tid & 63;
  const int brow = blockIdx.y * 128;
  const int bcol = blockIdx.x * 128;
  const int kbeg = blockIdx.z * 128;
  const int wr = wid >> 1, wc = wid & 1;
  const int l15 = lane & 15, l4 = lane >> 4;

  f32x4 acc[4][4] = {};
  const int foff = wid * 512 + lane * 8;

  for (int k0 = kbeg; k0 < kbeg + 128; k0 += 64) {
#pragma unroll
    for (int c = 0; c < 4; ++c) {
      int f = c * 2048 + foff;
      int r = f >> 6, kc = f & 63;
      gload_lds16(owt + (size_t)(brow + r) * 1024 + k0 + kc, As + c * 2048 + wid * 512);
    }
#pragma unroll
    for (int c = 0; c < 4; ++c) {
      int f = c * 2048 + foff;
      int r = f >> 6, kc = f & 63;
      gload_lds16(mvb + (size_t)(bcol + r) * 1024 + k0 + kc, Bs + c * 2048 + wid * 512);
    }
    __syncthreads();
#pragma unroll
    for (int kk = 0; kk < 2; ++kk) {
      const int ko = kk * 32 + l4 * 8;
      bf16x8 af[4], bfv[4];
#pragma unroll
      for (int m = 0; m < 4; ++m)
        af[m] = *(const bf16x8*)(As + (wr * 64 + m * 16 + l15) * 64 + ko);
#pragma unroll
      for (int n = 0; n < 4; ++n)
        bfv[n] = *(const bf16x8*)(Bs + (wc * 64 + n * 16 + l15) * 64 + ko);
#pragma unroll
      for (int m = 0; m < 4; ++m)
#pragma unroll
        for (int n = 0; n < 4; ++n)
          acc[m][n] = __builtin_amdgcn_mfma_f32_16x16x32_bf16(af[m], bfv[n], acc[m][n], 0, 0, 0);
    }
    __syncthreads();
  }

  float* dst = w2p + (size_t)blockIdx.z * 524288;
#pragma unroll
  for (int m = 0; m < 4; ++m) {
    int row0 = brow + wr * 64 + m * 16 + l4 * 4;
#pragma unroll
    for (int j = 0; j < 4; ++j) {
      int row = row0 + j;
#pragma unroll
      for (int n = 0; n < 4; ++n) {
        int col = bcol + wc * 64 + n * 16 + l15;
        dst[(size_t)row * 512 + col] = acc[m][n][j];
      }
    }
  }
}

// ---------------- w2t[i] = bf16(decay * sum_s w2p[s][i]), 4 elems/thread
__global__ __launch_bounds__(256)
void w2_reduce(const float* __restrict__ w2p, unsigned short* __restrict__ w2t,
               const float* __restrict__ dec)
{
  const int i = (blockIdx.x * 256 + threadIdx.x) * 4;  // 512 blocks -> 524288 elems
  const float d = *dec;
  f32x4 s = {};
#pragma unroll
  for (int sl = 0; sl < 8; ++sl) {
    f32x4 p = *(const f32x4*)(w2p + (size_t)sl * 524288 + i);
    s[0] += p[0]; s[1] += p[1]; s[2] += p[2]; s[3] += p[3];
  }
  union { unsigned short u[4]; i32x2 v; } pk;
#pragma unroll
  for (int j = 0; j < 4; ++j) pk.u[j] = f2bf(s[j] * d);
  *(i32x2*)(w2t + i) = pk.v;
}

// ---------------- softmax over rows of 512 (scores already scaled*masked) -> bf16
__global__ __launch_bounds__(256)
void softmax_rows(const float* __restrict__ S, unsigned short* __restrict__ P)
{
  const int wid = threadIdx.x >> 6, lane = threadIdx.x & 63;
  const int row = blockIdx.x * 4 + wid;
  const size_t base = (size_t)row * 512 + lane * 8;
  f32x4 s0 = *(const f32x4*)(S + base);
  f32x4 s1 = *(const f32x4*)(S + base + 4);
  float v[8];
#pragma unroll
  for (int i = 0; i < 4; ++i) { v[i] = s0[i]; v[4 + i] = s1[i]; }
  float mx = v[0];
#pragma unroll
  for (int i = 1; i < 8; ++i) mx = fmaxf(mx, v[i]);
#pragma unroll
  for (int off = 32; off >= 1; off >>= 1) mx = fmaxf(mx, __shfl_xor(mx, off, 64));
  float sum = 0.0f;
#pragma unroll
  for (int i = 0; i < 8; ++i) { v[i] = __expf(v[i] - mx); sum += v[i]; }
#pragma unroll
  for (int off = 32; off >= 1; off >>= 1) sum += __shfl_xor(sum, off, 64);
  const float inv = 1.0f / sum;
  union { unsigned short u[8]; i32x4 vec; } pk;
#pragma unroll
  for (int i = 0; i < 8; ++i) pk.u[i] = f2bf(v[i] * inv);
  *(i32x4*)(P + base) = pk.vec;
}

// ---------------- q -> qb (bf16); upd -> cat[:,1024:2048] only if *flag
__global__ __launch_bounds__(256)
void cvt_q_upd(const float* __restrict__ q, const float* __restrict__ upd,
               unsigned short* __restrict__ qb, unsigned short* __restrict__ cat,
               const int* __restrict__ flag)
{
  int idx = blockIdx.x * 256 + threadIdx.x;  // 2097152 threads
  union { unsigned short u[8]; i32x4 vec; } pk;
  if (idx < 1048576) {
    size_t f = (size_t)idx * 8;
    f32x4 a = *(const f32x4*)(q + f);
    f32x4 b = *(const f32x4*)(q + f + 4);
#pragma unroll
    for (int i = 0; i < 4; ++i) { pk.u[i] = f2bf(a[i]); pk.u[4 + i] = f2bf(b[i]); }
    *(i32x4*)(qb + f) = pk.vec;
  } else {
    if (*flag == 0) return;  // upd feeds only the gate path
    size_t f = (size_t)(idx - 1048576) * 8;
    int row = (int)(f >> 10);
    int col = (int)(f & 1023);
    f32x4 a = *(const f32x4*)(upd + f);
    f32x4 b = *(const f32x4*)(upd + f + 4);
#pragma unroll
    for (int i = 0; i < 4; ++i) { pk.u[i] = f2bf(a[i]); pk.u[4 + i] = f2bf(b[i]); }
    *(i32x4*)(cat + (size_t)row * 2048 + 1024 + col) = pk.vec;
  }
}

// ---------------- mk -> kb and mv -> mvb (bf16), one launch (512 blocks)
__global__ __launch_bounds__(256)
void cvt2_kv(const float* __restrict__ mk, const float* __restrict__ mv,
             unsigned short* __restrict__ kb, unsigned short* __restrict__ mvb)
{
  int idx = blockIdx.x * 256 + threadIdx.x;  // 131072
  const float* in; unsigned short* out; int rel;
  if (idx < 65536) { in = mk; out = kb;  rel = idx; }
  else             { in = mv; out = mvb; rel = idx - 65536; }
  size_t f = (size_t)rel * 8;
  f32x4 a = *(const f32x4*)(in + f);
  f32x4 b = *(const f32x4*)(in + f + 4);
  union { unsigned short u[8]; i32x4 vec; } pk;
#pragma unroll
  for (int i = 0; i < 4; ++i) { pk.u[i] = f2bf(a[i]); pk.u[4 + i] = f2bf(b[i]); }
  *(i32x4*)(out + f) = pk.vec;
}

// ---------------- batched transpose f32[R,1024] -> bf16[1024,R]
// gw and mv parts only needed for the gate path (flag==1); ow always.
__global__ __launch_bounds__(256)
void transpose3(const float* __restrict__ gw, const float* __restrict__ ow,
                const float* __restrict__ mv,
                unsigned short* __restrict__ gwt, unsigned short* __restrict__ owt,
                unsigned short* __restrict__ vt,
                const int* __restrict__ flag)
{
  __shared__ float t[32][33];
  const int by = blockIdx.y;
  const float* in; unsigned short* out; int R, rb;
  if (by < 64) {
    if (*flag == 0) return;  // gate weights unused when gate path skipped
    in = gw; out = gwt; R = 2048; rb = by;
  }
  else if (by < 96) { in = ow; out = owt; R = 1024; rb = by - 64; }
  else {
    if (*flag == 0) return;  // vt only feeds the read-materialization (gate) path
    in = mv; out = vt;  R = 512;  rb = by - 96;
  }
  const int tx = threadIdx.x & 31, ty = threadIdx.x >> 5;
  const int c0 = blockIdx.x * 32, r0 = rb * 32;
#pragma unroll
  for (int i = 0; i < 4; ++i)
    t[ty + i * 8][tx] = in[(size_t)(r0 + ty + i * 8) * 1024 + c0 + tx];
  __syncthreads();
#pragma unroll
  for (int i = 0; i < 4; ++i)
    out[(size_t)(c0 + ty + i * 8) * R + r0 + tx] = f2bf(t[tx][ty + i * 8]);
}

// ---------------- LayerNorm over rows of 1024, block per row
// x = X[row]*(1 + gsum[row]/1024) + ob[col]; gsum==0 when gate path skipped.
__global__ __launch_bounds__(256)
void ln_rows(const float* __restrict__ X, const float* __restrict__ gsum,
             const float* __restrict__ ob,
             const float* __restrict__ gamma, const float* __restrict__ beta,
             float* __restrict__ Y)
{
  const int row = blockIdx.x;
  const int tid = threadIdx.x;
  const size_t base = (size_t)row * 1024 + tid * 4;
  const float scl = 1.0f + gsum[row] * (1.0f / 1024.0f);
  f32x4 x = *(const f32x4*)(X + base);
  f32x4 bo = *(const f32x4*)(ob + tid * 4);
#pragma unroll
  for (int i = 0; i < 4; ++i) x[i] = x[i] * scl + bo[i];
  float s = x[0] + x[1] + x[2] + x[3];
  float q = x[0] * x[0] + x[1] * x[1] + x[2] * x[2] + x[3] * x[3];
#pragma unroll
  for (int off = 32; off >= 1; off >>= 1) {
    s += __shfl_xor(s, off, 64);
    q += __shfl_xor(q, off, 64);
  }
  __shared__ float ss[4], qq[4];
  const int wid = tid >> 6, lane = tid & 63;
  if (lane == 0) { ss[wid] = s; qq[wid] = q; }
  __syncthreads();
  s = ss[0] + ss[1] + ss[2] + ss[3];
  q = qq[0] + qq[1] + qq[2] + qq[3];
  const float mu = s * (1.0f / 1024.0f);
  const float var = q * (1.0f / 1024.0f) - mu * mu;
  const float r = rsqrtf(var + 1e-5f);
  f32x4 g = *(const f32x4*)(gamma + tid * 4);
  f32x4 b = *(const f32x4*)(beta + tid * 4);
  f32x4 y;
#pragma unroll
  for (int i = 0; i < 4; ++i) y[i] = (x[i] - mu) * r * g[i] + b[i];
  *(f32x4*)(Y + base) = y;
}

// ---------------- launch ----------------
extern "C" void kernel_launch(void* const* d_in, const int* in_sizes, int n_in,
                              void* d_out, int out_size, void* d_ws, size_t ws_size,
                              hipStream_t stream)
{
  (void)in_sizes; (void)n_in; (void)out_size; (void)ws_size;
  const float* q   = (const float*)d_in[0];   // [8192,1024]
  const float* mw  = (const float*)d_in[1];   // [8192,512]
  const float* upd = (const float*)d_in[2];   // [8192,1024]
  const float* mk  = (const float*)d_in[3];   // [512,1024]
  const float* mv  = (const float*)d_in[4];   // [512,1024]
  const float* dec = (const float*)d_in[5];   // scalar
  const float* gw  = (const float*)d_in[6];   // [2048,1024]
  const float* gb  = (const float*)d_in[7];   // [1024]
  const float* ow  = (const float*)d_in[8];   // [1024,1024]
  const float* ob  = (const float*)d_in[9];   // [1024]
  const float* lg  = (const float*)d_in[10];  // [1024]
  const float* lb  = (const float*)d_in[11];  // [1024]
  float* outp = (float*)d_out;
  char* ws = (char*)d_ws;

  // workspace layout (bytes); outpre overlays qb+scores after both are dead
  unsigned short* qb     = (unsigned short*)(ws + 0);          // 16.78 MB
  float*          scores = (float*)(ws + 16777216);            // 16.78 MB
  float*          outpre = (float*)(ws + 0);                   // 33.55 MB (reuse)
  unsigned short* kb     = (unsigned short*)(ws + 33554432);   // 1.05 MB
  unsigned short* vt     = (unsigned short*)(ws + 34603008);   // 1.05 MB
  unsigned short* gwt    = (unsigned short*)(ws + 35651584);   // 4.19 MB
  unsigned short* owt    = (unsigned short*)(ws + 39845888);   // 2.10 MB
  unsigned short* cat    = (unsigned short*)(ws + 41943040);   // 33.55 MB [8192,2048]
  unsigned short* probs  = (unsigned short*)(ws + 75497472);   // 8.39 MB
  float*          gsum   = (float*)(ws + 83886080);            // 32 KB
  int*            flag   = (int*)(ws + 83918848);              // 4 B
  unsigned short* mvb    = (unsigned short*)(ws + 84934656);   // 1.05 MB [512,1024] bf16
  unsigned short* w2t    = (unsigned short*)(ws + 85983232);   // 1.05 MB [1024,512] bf16
  float*          w2p    = (float*)(ws + 87031808);            // 16.78 MB [8][1024*512] f32
  // total ~104 MB

  // 0) flag = (out_b != 0); zero gsum
  check_bias_zero<<<33, 256, 0, stream>>>(ob, flag, gsum);

  // prep
  cvt_q_upd<<<8192, 256, 0, stream>>>(q, upd, qb, cat, flag);
  cvt2_kv<<<512, 256, 0, stream>>>(mk, mv, kb, mvb);
  transpose3<<<dim3(32, 112), 256, 0, stream>>>(gw, ow, mv, gwt, owt, vt, flag);

  // 1) scores = (qb x kb^T) * (1/sqrt(128)) * mw  [8192,512], K=1024
  gemm_bt<4, 64><<<dim3(8, 64), 256, 0, stream>>>(qb, 1024, kb, 1024, 1024, 512,
                                                  scores, nullptr, 0, mw, nullptr, nullptr, nullptr);
  // 2) probs = softmax(scores) -> bf16
  softmax_rows<<<2048, 256, 0, stream>>>(scores, probs);
  // 3) W2 = decay * (mv @ ow), stored as w2t[m,n]=(mv@ow)[n,m]*decay.
  //    Split-K over 8 slices (256 blocks, full machine) + reduce.
  w2_partial<<<dim3(4, 8, 8), 256, 0, stream>>>(owt, mvb, w2p);
  w2_reduce<<<512, 256, 0, stream>>>(w2p, w2t, dec);
  // 4) [flag only] read = probs x vt^T * decay -> bf16 into cat[:, :1024]
  gemm_bt<1, 128><<<dim3(8, 64), 256, 0, stream>>>(probs, 512, vt, 512, 512, 1024,
                                                   nullptr, cat, 2048, nullptr, nullptr, dec, flag);
  // 5) [flag only] gate rowsums: sigmoid(cat x gwt^T + gb) -> gsum
  gemm_bt<2, 128><<<dim3(8, 64), 256, 0, stream>>>(cat, 2048, gwt, 2048, 2048, 1024,
                                                   nullptr, nullptr, 0, gb, gsum, nullptr, flag);
  // 6) outpre = probs x w2t^T  ( = (P@V')@ow by associativity )  [8192,1024], K=512
  gemm_bt<3, 128><<<dim3(8, 64), 256, 0, stream>>>(probs, 512, w2t, 512, 512, 1024,
                                                   outpre, nullptr, 0, nullptr, nullptr, nullptr, nullptr);
  // 7) LayerNorm (applies gate scale [=1 when skipped] + out bias) -> final output
  ln_rows<<<8192, 256, 0, stream>>>(outpre, gsum, ob, lg, lb, outp);
}

// Round 9
// 88.082 us; speedup vs baseline: 2.2115x; 1.1070x over previous
//
#include <hip/hip_runtime.h>
#include <hip/hip_bf16.h>

typedef __attribute__((ext_vector_type(8))) short bf16x8;
typedef __attribute__((ext_vector_type(4))) float f32x4;
typedef __attribute__((ext_vector_type(4))) int i32x4;
typedef __attribute__((ext_vector_type(2))) int i32x2;
typedef __attribute__((ext_vector_type(4))) unsigned short u16x4;

// ---------- helpers ----------
static __device__ __forceinline__ void gload_lds16(const void* g, void* l) {
  __builtin_amdgcn_global_load_lds((const __attribute__((address_space(1))) void*)g,
                                   (__attribute__((address_space(3))) void*)l,
                                   16, 0, 0);
}

// f32 -> bf16 bits, round-to-nearest-even
static __device__ __forceinline__ unsigned short f2bf(float x) {
  unsigned int u = __float_as_uint(x);
  u += 0x7fffu + ((u >> 16) & 1u);
  return (unsigned short)(u >> 16);
}
static __device__ __forceinline__ float bf2f(unsigned short u) {
  return __uint_as_float((unsigned int)u << 16);
}

// ---------------- prep mega-kernel (one launch, role-split by blockIdx):
// b==0      : flag = (max|out_b| != 0)
// b in 1..16: zero gsum+rowsum (16384 floats)
// b 17..528 : mk->kb, mv->mvb bf16 convert
// b 529..1552: ow[1024,1024] -> owt bf16 transpose (32x32 tiles)
// b 1553..5648: q -> qb bf16 convert
__global__ __launch_bounds__(256)
void prep(const float* __restrict__ ob, int* __restrict__ flag,
          float* __restrict__ zeros,
          const float* __restrict__ mk, const float* __restrict__ mv,
          unsigned short* __restrict__ kb, unsigned short* __restrict__ mvb,
          const float* __restrict__ ow, unsigned short* __restrict__ owt,
          const float* __restrict__ q, unsigned short* __restrict__ qb)
{
  __shared__ float t[32][33];
  const int b = blockIdx.x;
  const int tid = threadIdx.x;
  if (b == 0) {
    f32x4 v = *(const f32x4*)(ob + tid * 4);
    float mx = fmaxf(fmaxf(fabsf(v[0]), fabsf(v[1])), fmaxf(fabsf(v[2]), fabsf(v[3])));
#pragma unroll
    for (int off = 32; off >= 1; off >>= 1) mx = fmaxf(mx, __shfl_xor(mx, off, 64));
    __shared__ float sm[4];
    const int wid = tid >> 6, lane = tid & 63;
    if (lane == 0) sm[wid] = mx;
    __syncthreads();
    if (tid == 0) {
      float m = fmaxf(fmaxf(sm[0], sm[1]), fmaxf(sm[2], sm[3]));
      *flag = (m != 0.0f) ? 1 : 0;
    }
  } else if (b < 17) {
    f32x4 z = {};
    *(f32x4*)(zeros + (b - 1) * 1024 + tid * 4) = z;
  } else if (b < 529) {
    int idx = (b - 17) * 256 + tid;  // 131072
    const float* in; unsigned short* out; int rel;
    if (idx < 65536) { in = mk; out = kb;  rel = idx; }
    else             { in = mv; out = mvb; rel = idx - 65536; }
    size_t f = (size_t)rel * 8;
    f32x4 a = *(const f32x4*)(in + f);
    f32x4 c = *(const f32x4*)(in + f + 4);
    union { unsigned short u[8]; i32x4 vec; } pk;
#pragma unroll
    for (int i = 0; i < 4; ++i) { pk.u[i] = f2bf(a[i]); pk.u[4 + i] = f2bf(c[i]); }
    *(i32x4*)(out + f) = pk.vec;
  } else if (b < 1553) {
    int id = b - 529;
    const int bx = id & 31, by = id >> 5;
    const int tx = tid & 31, ty = tid >> 5;
    const int c0 = bx * 32, r0 = by * 32;
#pragma unroll
    for (int i = 0; i < 4; ++i)
      t[ty + i * 8][tx] = ow[(size_t)(r0 + ty + i * 8) * 1024 + c0 + tx];
    __syncthreads();
#pragma unroll
    for (int i = 0; i < 4; ++i)
      owt[(size_t)(c0 + ty + i * 8) * 1024 + r0 + tx] = f2bf(t[tx][ty + i * 8]);
  } else {
    int idx = (b - 1553) * 256 + tid;  // 1048576
    size_t f = (size_t)idx * 8;
    f32x4 a = *(const f32x4*)(q + f);
    f32x4 c = *(const f32x4*)(q + f + 4);
    union { unsigned short u[8]; i32x4 vec; } pk;
#pragma unroll
    for (int i = 0; i < 4; ++i) { pk.u[i] = f2bf(a[i]); pk.u[4 + i] = f2bf(c[i]); }
    *(i32x4*)(qb + f) = pk.vec;
  }
}

// ---------------- flag-gated prep (runs only when out_b != 0):
// b 0..4095   : upd -> cat[:,1024:2048] bf16
// b 4096..6143: gw[2048,1024] -> gwt transpose
// b 6144..6655: mv[512,1024] -> vt transpose
__global__ __launch_bounds__(256)
void prep_gated(const float* __restrict__ upd, unsigned short* __restrict__ cat,
                const float* __restrict__ gw, unsigned short* __restrict__ gwt,
                const float* __restrict__ mv, unsigned short* __restrict__ vt,
                const int* __restrict__ flag)
{
  if (*flag == 0) return;
  __shared__ float t[32][33];
  const int b = blockIdx.x;
  const int tid = threadIdx.x;
  if (b < 4096) {
    int idx = b * 256 + tid;
    size_t f = (size_t)idx * 8;
    int row = (int)(f >> 10);
    int col = (int)(f & 1023);
    f32x4 a = *(const f32x4*)(upd + f);
    f32x4 c = *(const f32x4*)(upd + f + 4);
    union { unsigned short u[8]; i32x4 vec; } pk;
#pragma unroll
    for (int i = 0; i < 4; ++i) { pk.u[i] = f2bf(a[i]); pk.u[4 + i] = f2bf(c[i]); }
    *(i32x4*)(cat + (size_t)row * 2048 + 1024 + col) = pk.vec;
  } else {
    const float* in; unsigned short* out; int R, id;
    if (b < 6144) { in = gw; out = gwt; R = 2048; id = b - 4096; }
    else          { in = mv; out = vt;  R = 512;  id = b - 6144; }
    const int bx = id & 31, by = id >> 5;
    const int tx = tid & 31, ty = tid >> 5;
    const int c0 = bx * 32, r0 = by * 32;
#pragma unroll
    for (int i = 0; i < 4; ++i)
      t[ty + i * 8][tx] = in[(size_t)(r0 + ty + i * 8) * 1024 + c0 + tx];
    __syncthreads();
#pragma unroll
    for (int i = 0; i < 4; ++i)
      out[(size_t)(c0 + ty + i * 8) * R + r0 + tx] = f2bf(t[tx][ty + i * 8]);
  }
}

// ---------------- GEMM: C[M,N] = A[M,K](bf16,row,lda) x Bt[N,K]^T(bf16,row,ldb)
// 128xBN tile (BN=128 or 64), BK=64, 256 threads = 4 waves (2x2).
// EPI 1: v = v * (*fscale) / rowsum[row]; write bf16 Cb     [read path, flag]
// EPI 2: sigmoid(v+bias[col]); row-sum -> atomicAdd rowsum  [gate path, flag]
// EPI 5: p = exp(v*rsqrt(128)*bias[row*Nd+col]); write bf16 Cb;
//        per-row exp-sum -> atomicAdd rowsum                [scores+exp fused]
// EPI 6: v = v / rowsum[row]; write bf16 Cb                 [P_u @ W2, normalize]
template <int EPI, int BN>
__global__ __launch_bounds__(256)
void gemm_bt(const unsigned short* __restrict__ A, int lda,
             const unsigned short* __restrict__ Bt, int ldb,
             int Kd, int Nd,
             unsigned short* __restrict__ Cb, int ldcb,
             const float* __restrict__ bias,
             float* __restrict__ rowsum,
             const float* __restrict__ fscale,
             const int* __restrict__ flag)
{
  if (flag != nullptr && *flag == 0) return;
  constexpr int NB = BN / 32;
  __shared__ unsigned short As[128 * 64];
  __shared__ unsigned short Bs[BN * 64];
  const int tid  = threadIdx.x;
  const int wid  = tid >> 6;
  const int lane = tid & 63;

  // T1 XCD swizzle (nwg % 8 == 0 -> bijective)
  const int nwg  = gridDim.x * gridDim.y;
  const int flat = blockIdx.y * gridDim.x + blockIdx.x;
  const int swz  = (flat & 7) * (nwg >> 3) + (flat >> 3);
  const int bx   = swz % gridDim.x;
  const int by   = swz / gridDim.x;

  const int brow = by * 128;
  const int bcol = bx * BN;
  const int wr = wid >> 1, wc = wid & 1;
  const int l15 = lane & 15, l4 = lane >> 4;

  f32x4 acc[4][NB] = {};
  const int foff = wid * 512 + lane * 8;

  for (int k0 = 0; k0 < Kd; k0 += 64) {
#pragma unroll
    for (int c = 0; c < 4; ++c) {
      int f = c * 2048 + foff;
      int r = f >> 6, kc = f & 63;
      gload_lds16(A + (size_t)(brow + r) * lda + k0 + kc, As + c * 2048 + wid * 512);
    }
#pragma unroll
    for (int c = 0; c < NB; ++c) {
      int f = c * 2048 + foff;
      int r = f >> 6, kc = f & 63;
      gload_lds16(Bt + (size_t)(bcol + r) * ldb + k0 + kc, Bs + c * 2048 + wid * 512);
    }
    __syncthreads();
#pragma unroll
    for (int kk = 0; kk < 2; ++kk) {
      const int ko = kk * 32 + l4 * 8;
      bf16x8 af[4], bfv[NB];
#pragma unroll
      for (int m = 0; m < 4; ++m)
        af[m] = *(const bf16x8*)(As + (wr * 64 + m * 16 + l15) * 64 + ko);
#pragma unroll
      for (int n = 0; n < NB; ++n)
        bfv[n] = *(const bf16x8*)(Bs + (wc * (BN / 2) + n * 16 + l15) * 64 + ko);
#pragma unroll
      for (int m = 0; m < 4; ++m)
#pragma unroll
        for (int n = 0; n < NB; ++n)
          acc[m][n] = __builtin_amdgcn_mfma_f32_16x16x32_bf16(af[m], bfv[n], acc[m][n], 0, 0, 0);
    }
    __syncthreads();
  }

  // C/D frag mapping (m89-verified): col = lane&15, row = (lane>>4)*4 + j
  if constexpr (EPI == 2) {
#pragma unroll
    for (int m = 0; m < 4; ++m) {
#pragma unroll
      for (int j = 0; j < 4; ++j) {
        float part = 0.0f;
#pragma unroll
        for (int n = 0; n < NB; ++n) {
          int col = bcol + wc * (BN / 2) + n * 16 + l15;
          float x = acc[m][n][j] + bias[col];
          part += 1.0f / (1.0f + __expf(-x));
        }
#pragma unroll
        for (int off = 1; off < 16; off <<= 1)
          part += __shfl_xor(part, off, 64);
        if (l15 == 0) {
          int row = brow + wr * 64 + m * 16 + l4 * 4 + j;
          atomicAdd(&rowsum[row], part);
        }
      }
    }
  } else if constexpr (EPI == 5) {
#pragma unroll
    for (int m = 0; m < 4; ++m) {
#pragma unroll
      for (int j = 0; j < 4; ++j) {
        int row = brow + wr * 64 + m * 16 + l4 * 4 + j;
        const float* mwrow = bias + (size_t)row * Nd;
        float part = 0.0f;
#pragma unroll
        for (int n = 0; n < NB; ++n) {
          int col = bcol + wc * (BN / 2) + n * 16 + l15;
          float p = __expf(acc[m][n][j] * 0.08838834764831845f * mwrow[col]);
          part += p;
          Cb[(size_t)row * ldcb + col] = f2bf(p);
        }
#pragma unroll
        for (int off = 1; off < 16; off <<= 1)
          part += __shfl_xor(part, off, 64);
        if (l15 == 0) atomicAdd(&rowsum[row], part);
      }
    }
  } else {
    float fs = 1.0f;
    if constexpr (EPI == 1) fs = *fscale;
#pragma unroll
    for (int m = 0; m < 4; ++m) {
      int row0 = brow + wr * 64 + m * 16 + l4 * 4;
#pragma unroll
      for (int j = 0; j < 4; ++j) {
        int row = row0 + j;
        const float rscl = fs / rowsum[row];
#pragma unroll
        for (int n = 0; n < NB; ++n) {
          int col = bcol + wc * (BN / 2) + n * 16 + l15;
          Cb[(size_t)row * ldcb + col] = f2bf(acc[m][n][j] * rscl);
        }
      }
    }
  }
}

// ---------------- w2 split-K partial (grid 4,8,8 = 256 blocks)
__global__ __launch_bounds__(256)
void w2_partial(const unsigned short* __restrict__ owt,
                const unsigned short* __restrict__ mvb,
                float* __restrict__ w2p)
{
  __shared__ unsigned short As[128 * 64];
  __shared__ unsigned short Bs[128 * 64];
  const int tid  = threadIdx.x;
  const int wid  = tid >> 6;
  const int lane = tid & 63;
  const int brow = blockIdx.y * 128;
  const int bcol = blockIdx.x * 128;
  const int kbeg = blockIdx.z * 128;
  const int wr = wid >> 1, wc = wid & 1;
  const int l15 = lane & 15, l4 = lane >> 4;

  f32x4 acc[4][4] = {};
  const int foff = wid * 512 + lane * 8;

  for (int k0 = kbeg; k0 < kbeg + 128; k0 += 64) {
#pragma unroll
    for (int c = 0; c < 4; ++c) {
      int f = c * 2048 + foff;
      int r = f >> 6, kc = f & 63;
      gload_lds16(owt + (size_t)(brow + r) * 1024 + k0 + kc, As + c * 2048 + wid * 512);
    }
#pragma unroll
    for (int c = 0; c < 4; ++c) {
      int f = c * 2048 + foff;
      int r = f >> 6, kc = f & 63;
      gload_lds16(mvb + (size_t)(bcol + r) * 1024 + k0 + kc, Bs + c * 2048 + wid * 512);
    }
    __syncthreads();
#pragma unroll
    for (int kk = 0; kk < 2; ++kk) {
      const int ko = kk * 32 + l4 * 8;
      bf16x8 af[4], bfv[4];
#pragma unroll
      for (int m = 0; m < 4; ++m)
        af[m] = *(const bf16x8*)(As + (wr * 64 + m * 16 + l15) * 64 + ko);
#pragma unroll
      for (int n = 0; n < 4; ++n)
        bfv[n] = *(const bf16x8*)(Bs + (wc * 64 + n * 16 + l15) * 64 + ko);
#pragma unroll
      for (int m = 0; m < 4; ++m)
#pragma unroll
        for (int n = 0; n < 4; ++n)
          acc[m][n] = __builtin_amdgcn_mfma_f32_16x16x32_bf16(af[m], bfv[n], acc[m][n], 0, 0, 0);
    }
    __syncthreads();
  }

  float* dst = w2p + (size_t)blockIdx.z * 524288;
#pragma unroll
  for (int m = 0; m < 4; ++m) {
    int row0 = brow + wr * 64 + m * 16 + l4 * 4;
#pragma unroll
    for (int j = 0; j < 4; ++j) {
      int row = row0 + j;
#pragma unroll
      for (int n = 0; n < 4; ++n) {
        int col = bcol + wc * 64 + n * 16 + l15;
        dst[(size_t)row * 512 + col] = acc[m][n][j];
      }
    }
  }
}

// ---------------- w2t[i] = bf16(decay * sum_s w2p[s][i])
__global__ __launch_bounds__(256)
void w2_reduce(const float* __restrict__ w2p, unsigned short* __restrict__ w2t,
               const float* __restrict__ dec)
{
  const int i = (blockIdx.x * 256 + threadIdx.x) * 4;
  const float d = *dec;
  f32x4 s = {};
#pragma unroll
  for (int sl = 0; sl < 8; ++sl) {
    f32x4 p = *(const f32x4*)(w2p + (size_t)sl * 524288 + i);
    s[0] += p[0]; s[1] += p[1]; s[2] += p[2]; s[3] += p[3];
  }
  union { unsigned short u[4]; i32x2 v; } pk;
#pragma unroll
  for (int j = 0; j < 4; ++j) pk.u[j] = f2bf(s[j] * d);
  *(i32x2*)(w2t + i) = pk.v;
}

// ---------------- LayerNorm over rows of 1024 (bf16 input), block per row
// x = X[row]*(1 + gsum[row]/1024) + ob[col]; gsum==0 when gate path skipped.
__global__ __launch_bounds__(256)
void ln_rows(const unsigned short* __restrict__ X, const float* __restrict__ gsum,
             const float* __restrict__ ob,
             const float* __restrict__ gamma, const float* __restrict__ beta,
             float* __restrict__ Y)
{
  const int row = blockIdx.x;
  const int tid = threadIdx.x;
  const size_t base = (size_t)row * 1024 + tid * 4;
  const float scl = 1.0f + gsum[row] * (1.0f / 1024.0f);
  u16x4 xr = *(const u16x4*)(X + base);
  f32x4 bo = *(const f32x4*)(ob + tid * 4);
  float x[4];
#pragma unroll
  for (int i = 0; i < 4; ++i) x[i] = bf2f(xr[i]) * scl + bo[i];
  float s = x[0] + x[1] + x[2] + x[3];
  float q = x[0] * x[0] + x[1] * x[1] + x[2] * x[2] + x[3] * x[3];
#pragma unroll
  for (int off = 32; off >= 1; off >>= 1) {
    s += __shfl_xor(s, off, 64);
    q += __shfl_xor(q, off, 64);
  }
  __shared__ float ss[4], qq[4];
  const int wid = tid >> 6, lane = tid & 63;
  if (lane == 0) { ss[wid] = s; qq[wid] = q; }
  __syncthreads();
  s = ss[0] + ss[1] + ss[2] + ss[3];
  q = qq[0] + qq[1] + qq[2] + qq[3];
  const float mu = s * (1.0f / 1024.0f);
  const float var = q * (1.0f / 1024.0f) - mu * mu;
  const float r = rsqrtf(var + 1e-5f);
  f32x4 g = *(const f32x4*)(gamma + tid * 4);
  f32x4 b = *(const f32x4*)(beta + tid * 4);
  f32x4 y;
#pragma unroll
  for (int i = 0; i < 4; ++i) y[i] = (x[i] - mu) * r * g[i] + b[i];
  *(f32x4*)(Y + base) = y;
}

// ---------------- launch ----------------
extern "C" void kernel_launch(void* const* d_in, const int* in_sizes, int n_in,
                              void* d_out, int out_size, void* d_ws, size_t ws_size,
                              hipStream_t stream)
{
  (void)in_sizes; (void)n_in; (void)out_size; (void)ws_size;
  const float* q   = (const float*)d_in[0];   // [8192,1024]
  const float* mw  = (const float*)d_in[1];   // [8192,512]
  const float* upd = (const float*)d_in[2];   // [8192,1024]
  const float* mk  = (const float*)d_in[3];   // [512,1024]
  const float* mv  = (const float*)d_in[4];   // [512,1024]
  const float* dec = (const float*)d_in[5];   // scalar
  const float* gw  = (const float*)d_in[6];   // [2048,1024]
  const float* gb  = (const float*)d_in[7];   // [1024]
  const float* ow  = (const float*)d_in[8];   // [1024,1024]
  const float* ob  = (const float*)d_in[9];   // [1024]
  const float* lg  = (const float*)d_in[10];  // [1024]
  const float* lb  = (const float*)d_in[11];  // [1024]
  float* outp = (float*)d_out;
  char* ws = (char*)d_ws;

  // workspace layout (bytes)
  unsigned short* qb     = (unsigned short*)(ws + 0);          // 16.78 MB
  unsigned short* probs  = (unsigned short*)(ws + 16777216);   // 8.39 MB  [8192,512] bf16 (unnormalized exp)
  unsigned short* outpre = (unsigned short*)(ws + 25165824);   // 16.78 MB [8192,1024] bf16
  unsigned short* kb     = (unsigned short*)(ws + 41943040);   // 1.05 MB
  unsigned short* mvb    = (unsigned short*)(ws + 42991616);   // 1.05 MB
  unsigned short* owt    = (unsigned short*)(ws + 44040192);   // 2.10 MB
  unsigned short* w2t    = (unsigned short*)(ws + 46137344);   // 1.05 MB
  float*          w2p    = (float*)(ws + 47185920);            // 16.78 MB
  unsigned short* vt     = (unsigned short*)(ws + 63963136);   // 1.05 MB (flag path)
  unsigned short* gwt    = (unsigned short*)(ws + 65011712);   // 4.19 MB (flag path)
  unsigned short* cat    = (unsigned short*)(ws + 69206016);   // 33.55 MB (flag path)
  float*          gsum   = (float*)(ws + 102760448);           // 32 KB
  float*          rowsum = (float*)(ws + 102793216);           // 32 KB (exp row sums)
  int*            flag   = (int*)(ws + 102825984);             // 4 B
  // total ~103 MB

  // 1) prep: flag, zero gsum+rowsum, kb/mvb cvt, ow transpose, q cvt
  prep<<<5649, 256, 0, stream>>>(ob, flag, gsum, mk, mv, kb, mvb, ow, owt, q, qb);
  // 2) flag-gated prep: upd cvt, gw/mv transposes (no-op when out_b==0)
  prep_gated<<<6656, 256, 0, stream>>>(upd, cat, gw, gwt, mv, vt, flag);

  // 3) probs_u = exp((qb x kb^T)/sqrt(128) * mw) bf16; rowsum = per-row exp sums
  gemm_bt<5, 64><<<dim3(8, 64), 256, 0, stream>>>(qb, 1024, kb, 1024, 1024, 512,
                                                  probs, 512, mw, rowsum, nullptr, nullptr);
  // 4) W2 = decay * (mv @ ow) via split-K (256 blocks) + reduce
  w2_partial<<<dim3(4, 8, 8), 256, 0, stream>>>(owt, mvb, w2p);
  w2_reduce<<<512, 256, 0, stream>>>(w2p, w2t, dec);
  // 5) [flag only] read = (probs_u/rowsum) x vt^T * decay -> bf16 cat[:, :1024]
  gemm_bt<1, 128><<<dim3(8, 64), 256, 0, stream>>>(probs, 512, vt, 512, 512, 1024,
                                                   cat, 2048, nullptr, rowsum, dec, flag);
  // 6) [flag only] gate rowsums: sigmoid(cat x gwt^T + gb) -> gsum
  gemm_bt<2, 128><<<dim3(8, 64), 256, 0, stream>>>(cat, 2048, gwt, 2048, 2048, 1024,
                                                   nullptr, 0, gb, gsum, nullptr, flag);
  // 7) outpre = (probs_u x w2t^T) / rowsum  bf16  [8192,1024], K=512
  gemm_bt<6, 128><<<dim3(8, 64), 256, 0, stream>>>(probs, 512, w2t, 512, 512, 1024,
                                                   outpre, 1024, nullptr, rowsum, nullptr, nullptr);
  // 8) LayerNorm (gate scale [=1 when skipped] + out bias fused) -> final output
  ln_rows<<<8192, 256, 0, stream>>>(outpre, gsum, ob, lg, lb, outp);
}

// Round 10
// 81.751 us; speedup vs baseline: 2.3828x; 1.0774x over previous
//
#include <hip/hip_runtime.h>
#include <hip/hip_bf16.h>

typedef __attribute__((ext_vector_type(8))) short bf16x8;
typedef __attribute__((ext_vector_type(4))) float f32x4;
typedef __attribute__((ext_vector_type(4))) int i32x4;
typedef __attribute__((ext_vector_type(2))) int i32x2;
typedef __attribute__((ext_vector_type(4))) unsigned short u16x4;

// ---------- helpers ----------
static __device__ __forceinline__ void gload_lds16(const void* g, void* l) {
  __builtin_amdgcn_global_load_lds((const __attribute__((address_space(1))) void*)g,
                                   (__attribute__((address_space(3))) void*)l,
                                   16, 0, 0);
}

static __device__ __forceinline__ unsigned short f2bf(float x) {
  unsigned int u = __float_as_uint(x);
  u += 0x7fffu + ((u >> 16) & 1u);
  return (unsigned short)(u >> 16);
}
static __device__ __forceinline__ float bf2f(unsigned short u) {
  return __uint_as_float((unsigned int)u << 16);
}

// ---------------- shared 128xBN GEMM core (BK=64, 4 waves 2x2, 16x16x32 bf16)
template <int BN>
static __device__ __forceinline__ void gemm_core(
    const unsigned short* __restrict__ A, int lda,
    const unsigned short* __restrict__ Bt, int ldb,
    int kbeg, int kend, int brow, int bcol,
    unsigned short* As, unsigned short* Bs,
    f32x4 (&acc)[4][BN / 32])
{
  constexpr int NB = BN / 32;
  const int tid = threadIdx.x;
  const int wid = tid >> 6, lane = tid & 63;
  const int wr = wid >> 1, wc = wid & 1;
  const int l15 = lane & 15, l4 = lane >> 4;
  const int foff = wid * 512 + lane * 8;

  for (int k0 = kbeg; k0 < kend; k0 += 64) {
#pragma unroll
    for (int c = 0; c < 4; ++c) {
      int f = c * 2048 + foff;
      gload_lds16(A + (size_t)(brow + (f >> 6)) * lda + k0 + (f & 63),
                  As + c * 2048 + wid * 512);
    }
#pragma unroll
    for (int c = 0; c < NB; ++c) {
      int f = c * 2048 + foff;
      gload_lds16(Bt + (size_t)(bcol + (f >> 6)) * ldb + k0 + (f & 63),
                  Bs + c * 2048 + wid * 512);
    }
    __syncthreads();
#pragma unroll
    for (int kk = 0; kk < 2; ++kk) {
      const int ko = kk * 32 + l4 * 8;
      bf16x8 af[4], bfv[NB];
#pragma unroll
      for (int m = 0; m < 4; ++m)
        af[m] = *(const bf16x8*)(As + (wr * 64 + m * 16 + l15) * 64 + ko);
#pragma unroll
      for (int n = 0; n < NB; ++n)
        bfv[n] = *(const bf16x8*)(Bs + (wc * (BN / 2) + n * 16 + l15) * 64 + ko);
#pragma unroll
      for (int m = 0; m < 4; ++m)
#pragma unroll
        for (int n = 0; n < NB; ++n)
          acc[m][n] = __builtin_amdgcn_mfma_f32_16x16x32_bf16(af[m], bfv[n], acc[m][n], 0, 0, 0);
    }
    __syncthreads();
  }
}

// ---------------- mega-prep (ONE launch; gated blocks compute flag locally)
// b==0        : flag = (max|out_b| != 0)  [for later launches]
// b 1..16     : zero gsum+rowsum (16384 floats)
// b 17..528   : mk->kb, mv->mvb bf16 convert
// b 529..1552 : ow[1024,1024] -> owt transpose
// b 1553..5648: q -> qb bf16 convert
// b 5649..12304 [gated, local flag]: upd->cat cvt / gw->gwt / mv->vt transposes
__global__ __launch_bounds__(256)
void prep(const float* __restrict__ ob, int* __restrict__ flag,
          float* __restrict__ zeros,
          const float* __restrict__ mk, const float* __restrict__ mv,
          unsigned short* __restrict__ kb, unsigned short* __restrict__ mvb,
          const float* __restrict__ ow, unsigned short* __restrict__ owt,
          const float* __restrict__ q, unsigned short* __restrict__ qb,
          const float* __restrict__ upd, unsigned short* __restrict__ cat,
          const float* __restrict__ gw, unsigned short* __restrict__ gwt,
          unsigned short* __restrict__ vt)
{
  __shared__ float t[32][33];
  const int b = blockIdx.x;
  const int tid = threadIdx.x;
  if (b == 0) {
    f32x4 v = *(const f32x4*)(ob + tid * 4);
    float mx = fmaxf(fmaxf(fabsf(v[0]), fabsf(v[1])), fmaxf(fabsf(v[2]), fabsf(v[3])));
#pragma unroll
    for (int off = 32; off >= 1; off >>= 1) mx = fmaxf(mx, __shfl_xor(mx, off, 64));
    __shared__ float sm[4];
    const int wid = tid >> 6, lane = tid & 63;
    if (lane == 0) sm[wid] = mx;
    __syncthreads();
    if (tid == 0) {
      float m = fmaxf(fmaxf(sm[0], sm[1]), fmaxf(sm[2], sm[3]));
      *flag = (m != 0.0f) ? 1 : 0;
    }
  } else if (b < 17) {
    f32x4 z = {};
    *(f32x4*)(zeros + (b - 1) * 1024 + tid * 4) = z;
  } else if (b < 529) {
    int idx = (b - 17) * 256 + tid;
    const float* in; unsigned short* out; int rel;
    if (idx < 65536) { in = mk; out = kb;  rel = idx; }
    else             { in = mv; out = mvb; rel = idx - 65536; }
    size_t f = (size_t)rel * 8;
    f32x4 a = *(const f32x4*)(in + f);
    f32x4 c = *(const f32x4*)(in + f + 4);
    union { unsigned short u[8]; i32x4 vec; } pk;
#pragma unroll
    for (int i = 0; i < 4; ++i) { pk.u[i] = f2bf(a[i]); pk.u[4 + i] = f2bf(c[i]); }
    *(i32x4*)(out + f) = pk.vec;
  } else if (b < 1553) {
    int id = b - 529;
    const int bx = id & 31, by = id >> 5;
    const int tx = tid & 31, ty = tid >> 5;
    const int c0 = bx * 32, r0 = by * 32;
#pragma unroll
    for (int i = 0; i < 4; ++i)
      t[ty + i * 8][tx] = ow[(size_t)(r0 + ty + i * 8) * 1024 + c0 + tx];
    __syncthreads();
#pragma unroll
    for (int i = 0; i < 4; ++i)
      owt[(size_t)(c0 + ty + i * 8) * 1024 + r0 + tx] = f2bf(t[tx][ty + i * 8]);
  } else if (b < 5649) {
    int idx = (b - 1553) * 256 + tid;
    size_t f = (size_t)idx * 8;
    f32x4 a = *(const f32x4*)(q + f);
    f32x4 c = *(const f32x4*)(q + f + 4);
    union { unsigned short u[8]; i32x4 vec; } pk;
#pragma unroll
    for (int i = 0; i < 4; ++i) { pk.u[i] = f2bf(a[i]); pk.u[4 + i] = f2bf(c[i]); }
    *(i32x4*)(qb + f) = pk.vec;
  } else {
    // gated roles: compute the need-flag locally (no intra-launch dependency)
    f32x4 v = *(const f32x4*)(ob + tid * 4);
    float mx = fmaxf(fmaxf(fabsf(v[0]), fabsf(v[1])), fmaxf(fabsf(v[2]), fabsf(v[3])));
#pragma unroll
    for (int off = 32; off >= 1; off >>= 1) mx = fmaxf(mx, __shfl_xor(mx, off, 64));
    __shared__ float sm2[4];
    const int wid = tid >> 6, lane = tid & 63;
    if (lane == 0) sm2[wid] = mx;
    __syncthreads();
    float m = fmaxf(fmaxf(sm2[0], sm2[1]), fmaxf(sm2[2], sm2[3]));
    if (m == 0.0f) return;  // fast path: gate pipeline dead through zero out-bias
    __syncthreads();
    int g = b - 5649;
    if (g < 4096) {
      int idx = g * 256 + tid;
      size_t f = (size_t)idx * 8;
      int row = (int)(f >> 10);
      int col = (int)(f & 1023);
      f32x4 a = *(const f32x4*)(upd + f);
      f32x4 c = *(const f32x4*)(upd + f + 4);
      union { unsigned short u[8]; i32x4 vec; } pk;
#pragma unroll
      for (int i = 0; i < 4; ++i) { pk.u[i] = f2bf(a[i]); pk.u[4 + i] = f2bf(c[i]); }
      *(i32x4*)(cat + (size_t)row * 2048 + 1024 + col) = pk.vec;
    } else {
      const float* in; unsigned short* out; int R, id;
      if (g < 6144) { in = gw; out = gwt; R = 2048; id = g - 4096; }
      else          { in = mv; out = vt;  R = 512;  id = g - 6144; }
      const int bx = id & 31, by = id >> 5;
      const int tx = tid & 31, ty = tid >> 5;
      const int c0 = bx * 32, r0 = by * 32;
#pragma unroll
      for (int i = 0; i < 4; ++i)
        t[ty + i * 8][tx] = in[(size_t)(r0 + ty + i * 8) * 1024 + c0 + tx];
      __syncthreads();
#pragma unroll
      for (int i = 0; i < 4; ++i)
        out[(size_t)(c0 + ty + i * 8) * R + r0 + tx] = f2bf(t[tx][ty + i * 8]);
    }
  }
}

// ---------------- launch 2: w2 split-K partials (b<128, shadowed) + scores EPI5
// w2 role: b in [0,128): bx=b&3 (cols of mvb), by=(b>>2)&7 (rows of owt), bz=b>>5
//          (K slice of 256). Writes w2p[bz].
// scores:  b in [128,640): probs_u = exp((qb x kb^T)/sqrt(128)*mw) bf16,
//          rowsum += per-row exp sums. BN=64, XCD-swizzled over 512 blocks.
__global__ __launch_bounds__(256)
void k_scores_w2(const unsigned short* __restrict__ qb,
                 const unsigned short* __restrict__ kb,
                 const float* __restrict__ mw,
                 unsigned short* __restrict__ probs,
                 float* __restrict__ rowsum,
                 const unsigned short* __restrict__ owt,
                 const unsigned short* __restrict__ mvb,
                 float* __restrict__ w2p)
{
  __shared__ unsigned short As[128 * 64];
  __shared__ unsigned short Bs[128 * 64];
  const int b = blockIdx.x;
  const int tid = threadIdx.x;
  const int wid = tid >> 6, lane = tid & 63;
  const int wr = wid >> 1, wc = wid & 1;
  const int l15 = lane & 15, l4 = lane >> 4;

  if (b < 128) {
    const int brow = ((b >> 2) & 7) * 128;
    const int bcol = (b & 3) * 128;
    const int kbeg = (b >> 5) * 256;
    f32x4 acc[4][4] = {};
    gemm_core<128>(owt, 1024, mvb, 1024, kbeg, kbeg + 256, brow, bcol, As, Bs, acc);
    float* dst = w2p + (size_t)(b >> 5) * 524288;
#pragma unroll
    for (int m = 0; m < 4; ++m) {
      int row0 = brow + wr * 64 + m * 16 + l4 * 4;
#pragma unroll
      for (int j = 0; j < 4; ++j) {
#pragma unroll
        for (int n = 0; n < 4; ++n)
          dst[(size_t)(row0 + j) * 512 + bcol + wc * 64 + n * 16 + l15] = acc[m][n][j];
      }
    }
  } else {
    const int f = b - 128;                       // 0..511
    const int swz = (f & 7) * 64 + (f >> 3);     // XCD swizzle (512 % 8 == 0)
    const int bx = swz & 7, by = swz >> 3;
    const int brow = by * 128, bcol = bx * 64;
    f32x4 acc[4][2] = {};
    gemm_core<64>(qb, 1024, kb, 1024, 0, 1024, brow, bcol, As, Bs, acc);
#pragma unroll
    for (int m = 0; m < 4; ++m) {
#pragma unroll
      for (int j = 0; j < 4; ++j) {
        int row = brow + wr * 64 + m * 16 + l4 * 4 + j;
        const float* mwrow = mw + (size_t)row * 512;
        float part = 0.0f;
#pragma unroll
        for (int n = 0; n < 2; ++n) {
          int col = bcol + wc * 32 + n * 16 + l15;
          float p = __expf(acc[m][n][j] * 0.08838834764831845f * mwrow[col]);
          part += p;
          probs[(size_t)row * 512 + col] = f2bf(p);
        }
#pragma unroll
        for (int off = 1; off < 16; off <<= 1)
          part += __shfl_xor(part, off, 64);
        if (l15 == 0) atomicAdd(&rowsum[row], part);
      }
    }
  }
}

// ---------------- launch 3: w2 reduce (b<512) + [flag] read-GEMM into cat
__global__ __launch_bounds__(256)
void k_w2red_read(const float* __restrict__ w2p, unsigned short* __restrict__ w2t,
                  const float* __restrict__ dec,
                  const unsigned short* __restrict__ probs,
                  const unsigned short* __restrict__ vt,
                  unsigned short* __restrict__ cat,
                  const float* __restrict__ rowsum,
                  const int* __restrict__ flag)
{
  __shared__ unsigned short As[128 * 64];
  __shared__ unsigned short Bs[128 * 64];
  const int b = blockIdx.x;
  const int tid = threadIdx.x;
  if (b < 512) {
    const int i = (b * 256 + tid) * 4;
    const float d = *dec;
    f32x4 s = {};
#pragma unroll
    for (int sl = 0; sl < 4; ++sl) {
      f32x4 p = *(const f32x4*)(w2p + (size_t)sl * 524288 + i);
      s[0] += p[0]; s[1] += p[1]; s[2] += p[2]; s[3] += p[3];
    }
    union { unsigned short u[4]; i32x2 v; } pk;
#pragma unroll
    for (int j = 0; j < 4; ++j) pk.u[j] = f2bf(s[j] * d);
    *(i32x2*)(w2t + i) = pk.v;
  } else {
    if (*flag == 0) return;
    const int f = b - 512;
    const int swz = (f & 7) * 64 + (f >> 3);
    const int bx = swz & 7, by = swz >> 3;
    const int brow = by * 128, bcol = bx * 128;
    const int wid = tid >> 6, lane = tid & 63;
    const int wr = wid >> 1, wc = wid & 1;
    const int l15 = lane & 15, l4 = lane >> 4;
    f32x4 acc[4][4] = {};
    gemm_core<128>(probs, 512, vt, 512, 0, 512, brow, bcol, As, Bs, acc);
    const float d = *dec;
#pragma unroll
    for (int m = 0; m < 4; ++m) {
      int row0 = brow + wr * 64 + m * 16 + l4 * 4;
#pragma unroll
      for (int j = 0; j < 4; ++j) {
        int row = row0 + j;
        const float rscl = d / rowsum[row];
#pragma unroll
        for (int n = 0; n < 4; ++n) {
          int col = bcol + wc * 64 + n * 16 + l15;
          cat[(size_t)row * 2048 + col] = f2bf(acc[m][n][j] * rscl);
        }
      }
    }
  }
}

// ---------------- launch 4: EPI6 out-projection (b<512) + [flag] gate rowsums
__global__ __launch_bounds__(256)
void k_out_gate(const unsigned short* __restrict__ probs,
                const unsigned short* __restrict__ w2t,
                const float* __restrict__ rowsum,
                unsigned short* __restrict__ outpre,
                const unsigned short* __restrict__ cat,
                const unsigned short* __restrict__ gwt,
                const float* __restrict__ gb,
                float* __restrict__ gsum,
                const int* __restrict__ flag)
{
  __shared__ unsigned short As[128 * 64];
  __shared__ unsigned short Bs[128 * 64];
  const int b = blockIdx.x;
  const int tid = threadIdx.x;
  const int wid = tid >> 6, lane = tid & 63;
  const int wr = wid >> 1, wc = wid & 1;
  const int l15 = lane & 15, l4 = lane >> 4;

  if (b < 512) {
    const int swz = (b & 7) * 64 + (b >> 3);
    const int bx = swz & 7, by = swz >> 3;
    const int brow = by * 128, bcol = bx * 128;
    f32x4 acc[4][4] = {};
    gemm_core<128>(probs, 512, w2t, 512, 0, 512, brow, bcol, As, Bs, acc);
#pragma unroll
    for (int m = 0; m < 4; ++m) {
      int row0 = brow + wr * 64 + m * 16 + l4 * 4;
#pragma unroll
      for (int j = 0; j < 4; ++j) {
        int row = row0 + j;
        const float rscl = 1.0f / rowsum[row];
#pragma unroll
        for (int n = 0; n < 4; ++n) {
          int col = bcol + wc * 64 + n * 16 + l15;
          outpre[(size_t)row * 1024 + col] = f2bf(acc[m][n][j] * rscl);
        }
      }
    }
  } else {
    if (*flag == 0) return;
    const int f = b - 512;
    const int swz = (f & 7) * 64 + (f >> 3);
    const int bx = swz & 7, by = swz >> 3;
    const int brow = by * 128, bcol = bx * 128;
    f32x4 acc[4][4] = {};
    gemm_core<128>(cat, 2048, gwt, 2048, 0, 2048, brow, bcol, As, Bs, acc);
#pragma unroll
    for (int m = 0; m < 4; ++m) {
#pragma unroll
      for (int j = 0; j < 4; ++j) {
        float part = 0.0f;
#pragma unroll
        for (int n = 0; n < 4; ++n) {
          int col = bcol + wc * 64 + n * 16 + l15;
          float x = acc[m][n][j] + gb[col];
          part += 1.0f / (1.0f + __expf(-x));
        }
#pragma unroll
        for (int off = 1; off < 16; off <<= 1)
          part += __shfl_xor(part, off, 64);
        if (l15 == 0) {
          int row = brow + wr * 64 + m * 16 + l4 * 4 + j;
          atomicAdd(&gsum[row], part);
        }
      }
    }
  }
}

// ---------------- LayerNorm over rows of 1024 (bf16 input), block per row
// x = X[row]*(1 + gsum[row]/1024) + ob[col]; gsum==0 when gate path skipped.
__global__ __launch_bounds__(256)
void ln_rows(const unsigned short* __restrict__ X, const float* __restrict__ gsum,
             const float* __restrict__ ob,
             const float* __restrict__ gamma, const float* __restrict__ beta,
             float* __restrict__ Y)
{
  const int row = blockIdx.x;
  const int tid = threadIdx.x;
  const size_t base = (size_t)row * 1024 + tid * 4;
  const float scl = 1.0f + gsum[row] * (1.0f / 1024.0f);
  u16x4 xr = *(const u16x4*)(X + base);
  f32x4 bo = *(const f32x4*)(ob + tid * 4);
  float x[4];
#pragma unroll
  for (int i = 0; i < 4; ++i) x[i] = bf2f(xr[i]) * scl + bo[i];
  float s = x[0] + x[1] + x[2] + x[3];
  float q = x[0] * x[0] + x[1] * x[1] + x[2] * x[2] + x[3] * x[3];
#pragma unroll
  for (int off = 32; off >= 1; off >>= 1) {
    s += __shfl_xor(s, off, 64);
    q += __shfl_xor(q, off, 64);
  }
  __shared__ float ss[4], qq[4];
  const int wid = tid >> 6, lane = tid & 63;
  if (lane == 0) { ss[wid] = s; qq[wid] = q; }
  __syncthreads();
  s = ss[0] + ss[1] + ss[2] + ss[3];
  q = qq[0] + qq[1] + qq[2] + qq[3];
  const float mu = s * (1.0f / 1024.0f);
  const float var = q * (1.0f / 1024.0f) - mu * mu;
  const float r = rsqrtf(var + 1e-5f);
  f32x4 g = *(const f32x4*)(gamma + tid * 4);
  f32x4 bt = *(const f32x4*)(beta + tid * 4);
  f32x4 y;
#pragma unroll
  for (int i = 0; i < 4; ++i) y[i] = (x[i] - mu) * r * g[i] + bt[i];
  *(f32x4*)(Y + base) = y;
}

// ---------------- launch ----------------
extern "C" void kernel_launch(void* const* d_in, const int* in_sizes, int n_in,
                              void* d_out, int out_size, void* d_ws, size_t ws_size,
                              hipStream_t stream)
{
  (void)in_sizes; (void)n_in; (void)out_size; (void)ws_size;
  const float* q   = (const float*)d_in[0];   // [8192,1024]
  const float* mw  = (const float*)d_in[1];   // [8192,512]
  const float* upd = (const float*)d_in[2];   // [8192,1024]
  const float* mk  = (const float*)d_in[3];   // [512,1024]
  const float* mv  = (const float*)d_in[4];   // [512,1024]
  const float* dec = (const float*)d_in[5];   // scalar
  const float* gw  = (const float*)d_in[6];   // [2048,1024]
  const float* gb  = (const float*)d_in[7];   // [1024]
  const float* ow  = (const float*)d_in[8];   // [1024,1024]
  const float* ob  = (const float*)d_in[9];   // [1024]
  const float* lg  = (const float*)d_in[10];  // [1024]
  const float* lb  = (const float*)d_in[11];  // [1024]
  float* outp = (float*)d_out;
  char* ws = (char*)d_ws;

  // workspace layout (bytes)
  unsigned short* qb     = (unsigned short*)(ws + 0);          // 16.78 MB
  unsigned short* probs  = (unsigned short*)(ws + 16777216);   // 8.39 MB
  unsigned short* outpre = (unsigned short*)(ws + 25165824);   // 16.78 MB
  unsigned short* kb     = (unsigned short*)(ws + 41943040);   // 1.05 MB
  unsigned short* mvb    = (unsigned short*)(ws + 42991616);   // 1.05 MB
  unsigned short* owt    = (unsigned short*)(ws + 44040192);   // 2.10 MB
  unsigned short* w2t    = (unsigned short*)(ws + 46137344);   // 1.05 MB
  float*          w2p    = (float*)(ws + 47185920);            // 8.39 MB (4 slices)
  unsigned short* vt     = (unsigned short*)(ws + 55574528);   // 1.05 MB (flag path)
  unsigned short* gwt    = (unsigned short*)(ws + 56623104);   // 4.19 MB (flag path)
  unsigned short* cat    = (unsigned short*)(ws + 60817408);   // 33.55 MB (flag path)
  float*          gsum   = (float*)(ws + 94371840);            // 32 KB
  float*          rowsum = (float*)(ws + 94404608);            // 32 KB
  int*            flag   = (int*)(ws + 94437376);              // 4 B
  // total ~95 MB

  // 1) mega-prep: flag, zeroing, all conversions/transposes (+local-flag gated)
  prep<<<12305, 256, 0, stream>>>(ob, flag, gsum, mk, mv, kb, mvb, ow, owt,
                                  q, qb, upd, cat, gw, gwt, vt);
  // 2) w2 split-K partials (shadowed) + scores/exp/rowsum
  k_scores_w2<<<640, 256, 0, stream>>>(qb, kb, mw, probs, rowsum, owt, mvb, w2p);
  // 3) w2 reduce + [flag] read-GEMM into cat
  k_w2red_read<<<1024, 256, 0, stream>>>(w2p, w2t, dec, probs, vt, cat, rowsum, flag);
  // 4) out-projection (P_u x W2 / rowsum) + [flag] gate rowsums
  k_out_gate<<<1024, 256, 0, stream>>>(probs, w2t, rowsum, outpre, cat, gwt, gb, gsum, flag);
  // 5) LayerNorm (gate scale [=1 when skipped] + out bias fused) -> final output
  ln_rows<<<8192, 256, 0, stream>>>(outpre, gsum, ob, lg, lb, outp);
}